// Round 4
// baseline (1473.891 us; speedup 1.0000x reference)
//
#include <hip/hip_runtime.h>

#define B_ 8
#define N_ 1024
#define C_ 768
#define H_ 12
#define HD_ 64
#define NB_ 49
#define BH_ 96
#define SCALE_ 0.125f

typedef unsigned int u32;
typedef unsigned short u16;
typedef __attribute__((ext_vector_type(8))) short mfrag;   // 8 bf16 (4 VGPRs)
typedef __attribute__((ext_vector_type(4))) float f32x4;

__device__ __forceinline__ u16 f2bf(float x) {             // f32 -> bf16 (RNE)
    u32 u = __float_as_uint(x);
    u32 r = u + 0x7FFFu + ((u >> 16) & 1u);
    return (u16)(r >> 16);
}
__device__ __forceinline__ float bf2f(u16 h) { return __uint_as_float(((u32)h) << 16); }

// iRPE piecewise bucket (closed form for ALPHA=1.9, BETA=3.8, GAMMA=15.2):
// |d|: 0->0, 1->1, 2,3->2, >=4->3 ; bucket = 3 + sign(d)*g  (in [0,6])
__device__ __forceinline__ int lutf(int d) {
    int a = d < 0 ? -d : d;
    int gg = (a < 2 ? a : 2) + (a >= 4 ? 1 : 0);
    return d < 0 ? 3 - gg : 3 + gg;
}

// ---------------------------------------------------------------------------
// K0a: split q,k into per-head bf16 hi/lo buffers [bh][n][64]
// ---------------------------------------------------------------------------
__global__ void irpe_split_qk_k(const float* __restrict__ q, const float* __restrict__ k,
                                u16* __restrict__ qh, u16* __restrict__ ql,
                                u16* __restrict__ kh, u16* __restrict__ kl) {
    const int tid = blockIdx.x * 256 + threadIdx.x;
    const int o = tid * 4;
    const int bh = o >> 16, rem = o & 65535;
    const int n = rem >> 6, d = rem & 63;
    const int b = bh / H_, h = bh % H_;
    const size_t src = ((size_t)(b * N_ + n)) * C_ + h * HD_ + d;
    const float4 qv = *(const float4*)&q[src];
    const float4 kv = *(const float4*)&k[src];
    ushort4 a, c;
    a = make_ushort4(f2bf(qv.x), f2bf(qv.y), f2bf(qv.z), f2bf(qv.w));
    c = make_ushort4(f2bf(qv.x - bf2f(a.x)), f2bf(qv.y - bf2f(a.y)),
                     f2bf(qv.z - bf2f(a.z)), f2bf(qv.w - bf2f(a.w)));
    *(ushort4*)&qh[o] = a;
    *(ushort4*)&ql[o] = c;
    a = make_ushort4(f2bf(kv.x), f2bf(kv.y), f2bf(kv.z), f2bf(kv.w));
    c = make_ushort4(f2bf(kv.x - bf2f(a.x)), f2bf(kv.y - bf2f(a.y)),
                     f2bf(kv.z - bf2f(a.z)), f2bf(kv.w - bf2f(a.w)));
    *(ushort4*)&kh[o] = a;
    *(ushort4*)&kl[o] = c;
}

// ---------------------------------------------------------------------------
// K0b: v -> transposed bf16 hi/lo [bh][64(d)][1024(j)]
// ---------------------------------------------------------------------------
__global__ void irpe_vt_k(const float* __restrict__ v,
                          u16* __restrict__ vth, u16* __restrict__ vtl) {
    __shared__ float tile[64][65];
    const int bh = blockIdx.y, jc0 = blockIdx.x * 64;
    const int b = bh / H_, h = bh % H_;
    const int t = threadIdx.x;
#pragma unroll
    for (int rep = 0; rep < 4; ++rep) {
        const int fl = rep * 256 + t;
        const int jr = fl >> 4, c4 = (fl & 15) * 4;
        const float4 x = *(const float4*)&v[((size_t)(b * N_ + jc0 + jr)) * C_ + h * HD_ + c4];
        tile[jr][c4] = x.x; tile[jr][c4 + 1] = x.y; tile[jr][c4 + 2] = x.z; tile[jr][c4 + 3] = x.w;
    }
    __syncthreads();
    const int d = t >> 2, jq = (t & 3) * 16;
    u32 ph[8], pl[8];
#pragma unroll
    for (int jj = 0; jj < 8; ++jj) {
        const float x0 = tile[jq + jj * 2][d], x1 = tile[jq + jj * 2 + 1][d];
        const u16 h0 = f2bf(x0), h1 = f2bf(x1);
        const float r0 = x0 - bf2f(h0), r1 = x1 - bf2f(h1);
        ph[jj] = (u32)h0 | ((u32)h1 << 16);
        pl[jj] = (u32)f2bf(r0) | ((u32)f2bf(r1) << 16);
    }
    const size_t dst = (((size_t)bh * 64 + d) << 10) + jc0 + jq;
    *(uint4*)&vth[dst] = make_uint4(ph[0], ph[1], ph[2], ph[3]);
    *(uint4*)&vth[dst + 8] = make_uint4(ph[4], ph[5], ph[6], ph[7]);
    *(uint4*)&vtl[dst] = make_uint4(pl[0], pl[1], pl[2], pl[3]);
    *(uint4*)&vtl[dst + 8] = make_uint4(pl[4], pl[5], pl[6], pl[7]);
}

// ---------------------------------------------------------------------------
// K2: RPE tables. tk[bh][i][49] ; tqT[bh][49][1024] (pre-scaled)
// ---------------------------------------------------------------------------
__global__ void irpe_rpe_tables_k(const float* __restrict__ q, const float* __restrict__ k,
                                  const float* __restrict__ w_rpe_q, const float* __restrict__ w_rpe_k,
                                  float* __restrict__ tk, float* __restrict__ tqT) {
    const int bh = blockIdx.y, b = bh / H_, h = bh % H_;
    const int row0 = blockIdx.x * 4;
    __shared__ float qs[4][HD_], ks[4][HD_];
    const int t = threadIdx.x;
    {
        const int r = t >> 6, d = t & 63;
        const size_t gi = ((size_t)(b * N_ + row0 + r)) * C_ + h * HD_ + d;
        qs[r][d] = q[gi];
        ks[r][d] = k[gi];
    }
    __syncthreads();
    if (t < 4 * NB_) {
        const int r = t / NB_, u = t - r * NB_;
        float dk = 0.f, dq = 0.f;
#pragma unroll
        for (int d = 0; d < HD_; ++d) {
            dk = fmaf(qs[r][d], w_rpe_k[d * NB_ + u], dk);
            dq = fmaf(ks[r][d], w_rpe_q[d * NB_ + u], dq);
        }
        tk[((size_t)bh * N_ + row0 + r) * NB_ + u] = dk;
        tqT[(((size_t)bh * NB_ + u) << 10) + row0 + r] = dq * SCALE_;
    }
}

// ---------------------------------------------------------------------------
// K_main: single-sweep fused attention, bf16x3 MFMA, register-direct fragments.
// Block = (bh, 32 i-rows). 256 thr = 4 waves: mt=w&1 (16-row M-tile),
// jt0=(w>>1)*2 (QK j-tiles / PV d-tiles). 2 barriers per 64-col chunk.
// attn written unnormalized, rescaled in-kernel at the end (L2-hot).
// ---------------------------------------------------------------------------
__global__ __launch_bounds__(256, 3) void irpe_attn_mfma_k(
    const u16* __restrict__ qh_g, const u16* __restrict__ ql_g,
    const u16* __restrict__ kh_g, const u16* __restrict__ kl_g,
    const u16* __restrict__ vth_g, const u16* __restrict__ vtl_g,
    const float* __restrict__ tk, const float* __restrict__ tqT,
    const float* __restrict__ w_rpe_v,
    float* __restrict__ attn, float* __restrict__ pre) {
    __shared__ u16 awh[2048], awl[2048];     // e hi/lo [32][64] swizzled (8 KB)
    __shared__ float tq_s[NB_ * 68];         // tq slice [49][68] (13.3 KB)
    __shared__ float tks_s[32 * NB_];        // [32][49] (6.3 KB)
    __shared__ float bkt_s[32 * 50];         // [32][50] (6.4 KB)
    __shared__ float ssum_s[32];

    const int gid = blockIdx.x;
    const int bh = gid % BH_, itile = gid / BH_;   // bh%8 pins XCD
    const int b = bh / H_, h = bh % H_;
    const int i0 = itile * 32;
    const int yi = itile;                          // grid y of all 32 rows
    const int t = threadIdx.x;
    const int w = t >> 6, lane = t & 63;
    const int ln4 = lane >> 4, lh15 = lane & 15;
    const int mt = w & 1;
    const int jt0 = (w >> 1) * 2;
    const size_t tqbase = (size_t)bh * NB_ * 1024;
    const int arow0 = (bh << 10) + i0;

    // ---- Q fragments (persistent, direct global) ----
    mfrag qAh[2], qAl[2];
#pragma unroll
    for (int ks = 0; ks < 2; ++ks) {
        const size_t qa = (((size_t)(bh << 10) + i0 + mt * 16 + lh15) << 6) + (ln4 << 3) + (ks << 5);
        qAh[ks] = *(const mfrag*)&qh_g[qa];
        qAl[ks] = *(const mfrag*)&ql_g[qa];
    }

    // ---- K fragments for chunk 0 ----
    mfrag kFh[2][2], kFl[2][2];
#pragma unroll
    for (int ji = 0; ji < 2; ++ji)
#pragma unroll
        for (int ks = 0; ks < 2; ++ks) {
            const size_t a = (((size_t)(bh << 10) + ((jt0 + ji) << 4) + lh15) << 6) + (ln4 << 3) + (ks << 5);
            kFh[ji][ks] = *(const mfrag*)&kh_g[a];
            kFl[ji][ks] = *(const mfrag*)&kl_g[a];
        }

    // ---- tq(0) -> LDS ; tks -> LDS ; zero bkt/ssum ----
    f32x4 tqpre[4];
#pragma unroll
    for (int p = 0; p < 3; ++p) {
        const int unit = p * 256 + t, u = unit >> 4, j4 = unit & 15;
        tqpre[p] = *(const f32x4*)&tqT[tqbase + ((size_t)u << 10) + (j4 << 2)];
    }
    if (t < 16) tqpre[3] = *(const f32x4*)&tqT[tqbase + ((size_t)48 << 10) + (t << 2)];
#pragma unroll
    for (int p = 0; p < 3; ++p) {
        const int unit = p * 256 + t, u = unit >> 4, j4 = unit & 15;
        *(f32x4*)&tq_s[u * 68 + (j4 << 2)] = tqpre[p];
    }
    if (t < 16) *(f32x4*)&tq_s[48 * 68 + (t << 2)] = tqpre[3];
    {
        const size_t tkb = ((size_t)(bh << 10) + i0) * NB_;
        for (int idx = t; idx < 32 * NB_; idx += 256) tks_s[idx] = tk[tkb + idx];
    }
    for (int idx = t; idx < 1600; idx += 256) bkt_s[idx] = 0.f;
    if (t < 32) ssum_s[t] = 0.f;
    __syncthreads();

    f32x4 apv[2] = {{0.f, 0.f, 0.f, 0.f}, {0.f, 0.f, 0.f, 0.f}};
    float srow[4] = {0.f, 0.f, 0.f, 0.f};
    mfrag vFh[2][2], vFl[2][2];

#pragma unroll 1
    for (int ch = 0; ch < 16; ++ch) {
        const int jc0 = ch << 6;

        // ---- QK (bf16x3) from registers ----
        f32x4 aq[2];
#pragma unroll
        for (int ji = 0; ji < 2; ++ji) {
            f32x4 c = {0.f, 0.f, 0.f, 0.f};
            c = __builtin_amdgcn_mfma_f32_16x16x32_bf16(qAh[0], kFh[ji][0], c, 0, 0, 0);
            c = __builtin_amdgcn_mfma_f32_16x16x32_bf16(qAh[0], kFl[ji][0], c, 0, 0, 0);
            c = __builtin_amdgcn_mfma_f32_16x16x32_bf16(qAl[0], kFh[ji][0], c, 0, 0, 0);
            c = __builtin_amdgcn_mfma_f32_16x16x32_bf16(qAh[1], kFh[ji][1], c, 0, 0, 0);
            c = __builtin_amdgcn_mfma_f32_16x16x32_bf16(qAh[1], kFl[ji][1], c, 0, 0, 0);
            c = __builtin_amdgcn_mfma_f32_16x16x32_bf16(qAl[1], kFh[ji][1], c, 0, 0, 0);
            aq[ji] = c;
        }

        // ---- prefetch next K frags + next tq slice (regs) ----
        if (ch < 15) {
            const int jc1 = jc0 + 64;
#pragma unroll
            for (int ji = 0; ji < 2; ++ji)
#pragma unroll
                for (int ks = 0; ks < 2; ++ks) {
                    const size_t a = (((size_t)(bh << 10) + jc1 + ((jt0 + ji) << 4) + lh15) << 6) + (ln4 << 3) + (ks << 5);
                    kFh[ji][ks] = *(const mfrag*)&kh_g[a];
                    kFl[ji][ks] = *(const mfrag*)&kl_g[a];
                }
#pragma unroll
            for (int p = 0; p < 3; ++p) {
                const int unit = p * 256 + t, u = unit >> 4, j4 = unit & 15;
                tqpre[p] = *(const f32x4*)&tqT[tqbase + ((size_t)u << 10) + jc1 + (j4 << 2)];
            }
            if (t < 16) tqpre[3] = *(const f32x4*)&tqT[tqbase + ((size_t)48 << 10) + jc1 + (t << 2)];
        }

        // ---- V fragments for this chunk (direct global, early issue) ----
#pragma unroll
        for (int di = 0; di < 2; ++di)
#pragma unroll
            for (int ks = 0; ks < 2; ++ks) {
                const size_t a = (((size_t)(bh * 64) + ((jt0 + di) << 4) + lh15) << 10) + jc0 + (ln4 << 3) + (ks << 5);
                vFh[di][ks] = *(const mfrag*)&vth_g[a];
                vFl[di][ks] = *(const mfrag*)&vtl_g[a];
            }

        // ---- bias + exp + emit ----
#pragma unroll
        for (int ji = 0; ji < 2; ++ji) {
            const int jj = jt0 + ji;
            const int yj = (ch << 1) + (jj >> 1);
            const int by = lutf(yi - yj);
            const int xj = ((jj & 1) << 4) + lh15;
            const int jl = (jj << 4) + lh15;
#pragma unroll
            for (int r = 0; r < 4; ++r) {
                const int il = mt * 16 + ln4 * 4 + r;           // i_loc == xi
                const int bij = by * 7 + lutf(il - xj);
                const float e = __expf(fmaf(aq[ji][r], SCALE_,
                                            tks_s[il * NB_ + bij] + tq_s[(48 - bij) * 68 + jl]));
                srow[r] += e;
                atomicAdd(&bkt_s[il * 50 + bij], e);
                attn[((size_t)(arow0 + il) << 10) + jc0 + jl] = e;
                const u16 eh = f2bf(e);
                const int off = il * 128 + ((jl << 1) ^ ((il & 7) << 4));
                *(u16*)((char*)awh + off) = eh;
                *(u16*)((char*)awl + off) = f2bf(e - bf2f(eh));
            }
        }
        __syncthreads();   // B1: aw visible; tq_s(ch) reads done

        // ---- write next tq slice ----
        if (ch < 15) {
#pragma unroll
            for (int p = 0; p < 3; ++p) {
                const int unit = p * 256 + t, u = unit >> 4, j4 = unit & 15;
                *(f32x4*)&tq_s[u * 68 + (j4 << 2)] = tqpre[p];
            }
            if (t < 16) *(f32x4*)&tq_s[48 * 68 + (t << 2)] = tqpre[3];
        }

        // ---- PV (bf16x3): A from aw LDS, B from vF regs ----
        {
            const int rowA = mt * 16 + lh15, sa = (rowA & 7) << 4;
            mfrag pah[2], pal[2];
#pragma unroll
            for (int ji = 0; ji < 2; ++ji) {
                const int ba = rowA * 128 + ((((ln4 << 4) + (ji << 6))) ^ sa);
                pah[ji] = *(const mfrag*)((const char*)awh + ba);
                pal[ji] = *(const mfrag*)((const char*)awl + ba);
            }
#pragma unroll
            for (int di = 0; di < 2; ++di) {
                f32x4 c = apv[di];
                c = __builtin_amdgcn_mfma_f32_16x16x32_bf16(pah[0], vFh[di][0], c, 0, 0, 0);
                c = __builtin_amdgcn_mfma_f32_16x16x32_bf16(pah[0], vFl[di][0], c, 0, 0, 0);
                c = __builtin_amdgcn_mfma_f32_16x16x32_bf16(pal[0], vFh[di][0], c, 0, 0, 0);
                c = __builtin_amdgcn_mfma_f32_16x16x32_bf16(pah[1], vFh[di][1], c, 0, 0, 0);
                c = __builtin_amdgcn_mfma_f32_16x16x32_bf16(pah[1], vFl[di][1], c, 0, 0, 0);
                c = __builtin_amdgcn_mfma_f32_16x16x32_bf16(pal[1], vFh[di][1], c, 0, 0, 0);
                apv[di] = c;
            }
        }
        __syncthreads();   // B2: aw free; tq_s(ch+1) visible
    }

    // ---- epilogue: row sums ----
#pragma unroll
    for (int r = 0; r < 4; ++r) {
        float s = srow[r];
        s += __shfl_xor(s, 1); s += __shfl_xor(s, 2);
        s += __shfl_xor(s, 4); s += __shfl_xor(s, 8);
        if (lh15 == 0) atomicAdd(&ssum_s[mt * 16 + ln4 * 4 + r], s);
    }
    __syncthreads();

    // ---- rpe_v + normalize + write pre ----
    {
        const int d0 = (jt0 << 4) + lh15;
        f32x4 rv0 = {0.f, 0.f, 0.f, 0.f}, rv1 = {0.f, 0.f, 0.f, 0.f};
        for (int u = 0; u < NB_; ++u) {
            const float wv0 = w_rpe_v[u * 64 + d0];
            const float wv1 = w_rpe_v[u * 64 + 16 + d0];
#pragma unroll
            for (int r = 0; r < 4; ++r) {
                const float bv = bkt_s[(mt * 16 + ln4 * 4 + r) * 50 + u];
                rv0[r] += bv * wv0;
                rv1[r] += bv * wv1;
            }
        }
#pragma unroll
        for (int r = 0; r < 4; ++r) {
            const int il = mt * 16 + ln4 * 4 + r;
            const float inv = 1.0f / ssum_s[il];
            const size_t ob = ((size_t)(b * N_ + i0 + il)) * C_ + h * HD_;
            pre[ob + d0] = (apv[0][r] + rv0[r]) * inv;
            pre[ob + 16 + d0] = (apv[1][r] + rv1[r]) * inv;
        }
    }

    // ---- fused attn rescale (rows are L2-hot) ----
    for (int rep = 0; rep < 32; ++rep) {
        const float inv = 1.0f / ssum_s[rep];
        float4* p = (float4*)&attn[(size_t)(arow0 + rep) << 10];
        float4 x = p[t];
        x.x *= inv; x.y *= inv; x.z *= inv; x.w *= inv;
        p[t] = x;
    }
}

// ---------------------------------------------------------------------------
// K5: projection GEMM (f32): out[m,n] = pre[m,:] . proj_w[n,:] + bias[n]
// ---------------------------------------------------------------------------
__global__ void irpe_proj_gemm_k(const float* __restrict__ A, const float* __restrict__ Bw,
                                 const float* __restrict__ bias, float* __restrict__ Cout) {
    const int bm = blockIdx.x * 64, bn = blockIdx.y * 64;
    __shared__ float As[16][64];
    __shared__ float Bs[16][64];
    const int t = threadIdx.x;
    const int lr = t >> 2;
    const int lc = (t & 3) * 4;
    const int tx = t & 15, ty = t >> 4;
    float acc[4][4] = {{0.f}};

    for (int kt = 0; kt < C_; kt += 16) {
        const float4 av = *(const float4*)&A[(size_t)(bm + lr) * C_ + kt + lc];
        const float4 bv = *(const float4*)&Bw[(size_t)(bn + lr) * C_ + kt + lc];
        As[lc + 0][lr] = av.x; As[lc + 1][lr] = av.y; As[lc + 2][lr] = av.z; As[lc + 3][lr] = av.w;
        Bs[lc + 0][lr] = bv.x; Bs[lc + 1][lr] = bv.y; Bs[lc + 2][lr] = bv.z; Bs[lc + 3][lr] = bv.w;
        __syncthreads();
#pragma unroll
        for (int kk = 0; kk < 16; ++kk) {
            const float4 a = *(const float4*)&As[kk][ty * 4];
            const float4 b = *(const float4*)&Bs[kk][tx * 4];
            const float ar[4] = {a.x, a.y, a.z, a.w};
            const float br[4] = {b.x, b.y, b.z, b.w};
#pragma unroll
            for (int r = 0; r < 4; ++r)
#pragma unroll
                for (int c = 0; c < 4; ++c) acc[r][c] = fmaf(ar[r], br[c], acc[r][c]);
        }
        __syncthreads();
    }
#pragma unroll
    for (int r = 0; r < 4; ++r) {
        const int rowi = bm + ty * 4 + r;
#pragma unroll
        for (int c = 0; c < 4; ++c)
            Cout[(size_t)rowi * C_ + bn + tx * 4 + c] = acc[r][c] + bias[bn + tx * 4 + c];
    }
}

// ---------------------------------------------------------------------------
extern "C" void kernel_launch(void* const* d_in, const int* in_sizes, int n_in,
                              void* d_out, int out_size, void* d_ws, size_t ws_size,
                              hipStream_t stream) {
    const float* q       = (const float*)d_in[0];
    const float* k       = (const float*)d_in[1];
    const float* v       = (const float*)d_in[2];
    const float* w_rpe_q = (const float*)d_in[3];
    const float* w_rpe_k = (const float*)d_in[4];
    const float* w_rpe_v = (const float*)d_in[5];
    const float* proj_w  = (const float*)d_in[6];
    const float* proj_b  = (const float*)d_in[7];

    float* out  = (float*)d_out;               // [B,N,C]
    float* attn = out + (size_t)B_ * N_ * C_;  // [B,H,N,N]

    char* ws = (char*)d_ws;
    float* tk    = (float*)ws; ws += (size_t)BH_ * N_ * NB_ * 4;
    float* tqT   = (float*)ws; ws += (size_t)BH_ * NB_ * N_ * 4;
    float* pre   = (float*)ws; ws += (size_t)B_ * N_ * C_ * 4;
    u16* qh  = (u16*)ws; ws += (size_t)BH_ * N_ * 64 * 2;
    u16* ql  = (u16*)ws; ws += (size_t)BH_ * N_ * 64 * 2;
    u16* kh  = (u16*)ws; ws += (size_t)BH_ * N_ * 64 * 2;
    u16* kl  = (u16*)ws; ws += (size_t)BH_ * N_ * 64 * 2;
    u16* vth = (u16*)ws; ws += (size_t)BH_ * 64 * N_ * 2;
    u16* vtl = (u16*)ws; ws += (size_t)BH_ * 64 * N_ * 2;

    irpe_split_qk_k<<<6144, 256, 0, stream>>>(q, k, qh, ql, kh, kl);
    irpe_vt_k<<<dim3(16, BH_), 256, 0, stream>>>(v, vth, vtl);
    irpe_rpe_tables_k<<<dim3(N_ / 4, BH_), 256, 0, stream>>>(q, k, w_rpe_q, w_rpe_k, tk, tqT);

    irpe_attn_mfma_k<<<BH_ * (N_ / 32), 256, 0, stream>>>(
        qh, ql, kh, kl, vth, vtl, tk, tqT, w_rpe_v, attn, pre);

    irpe_proj_gemm_k<<<dim3((B_ * N_) / 64, C_ / 64), 256, 0, stream>>>(pre, proj_w, proj_b, out);
}

// Round 5
// 1267.422 us; speedup vs baseline: 1.1629x; 1.1629x over previous
//
#include <hip/hip_runtime.h>

#define B_ 8
#define N_ 1024
#define C_ 768
#define H_ 12
#define HD_ 64
#define NB_ 49
#define BH_ 96
#define SCALE_ 0.125f

typedef unsigned int u32;
typedef unsigned short u16;
typedef __attribute__((ext_vector_type(8))) short mfrag;   // 8 bf16 (4 VGPRs)
typedef __attribute__((ext_vector_type(4))) float f32x4;

__device__ __forceinline__ u16 f2bf(float x) {             // f32 -> bf16 (RNE)
    u32 u = __float_as_uint(x);
    u32 r = u + 0x7FFFu + ((u >> 16) & 1u);
    return (u16)(r >> 16);
}
__device__ __forceinline__ float bf2f(u16 h) { return __uint_as_float(((u32)h) << 16); }

// iRPE piecewise bucket (closed form for ALPHA=1.9, BETA=3.8, GAMMA=15.2):
// |d|: 0->0, 1->1, 2,3->2, >=4->3 ; bucket = 3 + sign(d)*g  (in [0,6])
__device__ __forceinline__ int lutf(int d) {
    int a = d < 0 ? -d : d;
    int gg = (a < 2 ? a : 2) + (a >= 4 ? 1 : 0);
    return d < 0 ? 3 - gg : 3 + gg;
}

// ---------------------------------------------------------------------------
// K0a: split q,k into per-head bf16 hi/lo buffers [bh][n][64]
// ---------------------------------------------------------------------------
__global__ void irpe_split_qk_k(const float* __restrict__ q, const float* __restrict__ k,
                                u16* __restrict__ qh, u16* __restrict__ ql,
                                u16* __restrict__ kh, u16* __restrict__ kl) {
    const int tid = blockIdx.x * 256 + threadIdx.x;
    const int o = tid * 4;
    const int bh = o >> 16, rem = o & 65535;
    const int n = rem >> 6, d = rem & 63;
    const int b = bh / H_, h = bh % H_;
    const size_t src = ((size_t)(b * N_ + n)) * C_ + h * HD_ + d;
    const float4 qv = *(const float4*)&q[src];
    const float4 kv = *(const float4*)&k[src];
    ushort4 a, c;
    a = make_ushort4(f2bf(qv.x), f2bf(qv.y), f2bf(qv.z), f2bf(qv.w));
    c = make_ushort4(f2bf(qv.x - bf2f(a.x)), f2bf(qv.y - bf2f(a.y)),
                     f2bf(qv.z - bf2f(a.z)), f2bf(qv.w - bf2f(a.w)));
    *(ushort4*)&qh[o] = a;
    *(ushort4*)&ql[o] = c;
    a = make_ushort4(f2bf(kv.x), f2bf(kv.y), f2bf(kv.z), f2bf(kv.w));
    c = make_ushort4(f2bf(kv.x - bf2f(a.x)), f2bf(kv.y - bf2f(a.y)),
                     f2bf(kv.z - bf2f(a.z)), f2bf(kv.w - bf2f(a.w)));
    *(ushort4*)&kh[o] = a;
    *(ushort4*)&kl[o] = c;
}

// ---------------------------------------------------------------------------
// K0b: v -> transposed bf16 hi/lo [bh][64(d)][1024(j)]
// ---------------------------------------------------------------------------
__global__ void irpe_vt_k(const float* __restrict__ v,
                          u16* __restrict__ vth, u16* __restrict__ vtl) {
    __shared__ float tile[64][65];
    const int bh = blockIdx.y, jc0 = blockIdx.x * 64;
    const int b = bh / H_, h = bh % H_;
    const int t = threadIdx.x;
#pragma unroll
    for (int rep = 0; rep < 4; ++rep) {
        const int fl = rep * 256 + t;
        const int jr = fl >> 4, c4 = (fl & 15) * 4;
        const float4 x = *(const float4*)&v[((size_t)(b * N_ + jc0 + jr)) * C_ + h * HD_ + c4];
        tile[jr][c4] = x.x; tile[jr][c4 + 1] = x.y; tile[jr][c4 + 2] = x.z; tile[jr][c4 + 3] = x.w;
    }
    __syncthreads();
    const int d = t >> 2, jq = (t & 3) * 16;
    u32 ph[8], pl[8];
#pragma unroll
    for (int jj = 0; jj < 8; ++jj) {
        const float x0 = tile[jq + jj * 2][d], x1 = tile[jq + jj * 2 + 1][d];
        const u16 h0 = f2bf(x0), h1 = f2bf(x1);
        const float r0 = x0 - bf2f(h0), r1 = x1 - bf2f(h1);
        ph[jj] = (u32)h0 | ((u32)h1 << 16);
        pl[jj] = (u32)f2bf(r0) | ((u32)f2bf(r1) << 16);
    }
    const size_t dst = (((size_t)bh * 64 + d) << 10) + jc0 + jq;
    *(uint4*)&vth[dst] = make_uint4(ph[0], ph[1], ph[2], ph[3]);
    *(uint4*)&vth[dst + 8] = make_uint4(ph[4], ph[5], ph[6], ph[7]);
    *(uint4*)&vtl[dst] = make_uint4(pl[0], pl[1], pl[2], pl[3]);
    *(uint4*)&vtl[dst + 8] = make_uint4(pl[4], pl[5], pl[6], pl[7]);
}

// ---------------------------------------------------------------------------
// K2: RPE tables. tk[bh][i][49] ; tqT[bh][49][1024] (pre-scaled)
// ---------------------------------------------------------------------------
__global__ void irpe_rpe_tables_k(const float* __restrict__ q, const float* __restrict__ k,
                                  const float* __restrict__ w_rpe_q, const float* __restrict__ w_rpe_k,
                                  float* __restrict__ tk, float* __restrict__ tqT) {
    const int bh = blockIdx.y, b = bh / H_, h = bh % H_;
    const int row0 = blockIdx.x * 4;
    __shared__ float qs[4][HD_], ks[4][HD_];
    const int t = threadIdx.x;
    {
        const int r = t >> 6, d = t & 63;
        const size_t gi = ((size_t)(b * N_ + row0 + r)) * C_ + h * HD_ + d;
        qs[r][d] = q[gi];
        ks[r][d] = k[gi];
    }
    __syncthreads();
    if (t < 4 * NB_) {
        const int r = t / NB_, u = t - r * NB_;
        float dk = 0.f, dq = 0.f;
#pragma unroll
        for (int d = 0; d < HD_; ++d) {
            dk = fmaf(qs[r][d], w_rpe_k[d * NB_ + u], dk);
            dq = fmaf(ks[r][d], w_rpe_q[d * NB_ + u], dq);
        }
        tk[((size_t)bh * N_ + row0 + r) * NB_ + u] = dk;
        tqT[(((size_t)bh * NB_ + u) << 10) + row0 + r] = dq * SCALE_;
    }
}

// ---------------------------------------------------------------------------
// K_main: single-sweep fused attention, bf16x3 MFMA.
// Block = (bh, 32 i-rows), bh XCD-pinned (12 bh per XCD, itile-inner order so
// per-XCD hot set ~3 bh ~2.7MB fits L2). 4 waves: mt=w&1 (16-row M-tile),
// jt0=(w>>1)*2 (QK j-tiles / PV d-tiles). 64-col chunks, 4 barriers/chunk.
// K LDS-staged with T14 async split (loads issued one chunk early); tq bias
// LDS-staged with reg-prefetch; V reg-loaded early, written to kv buffer.
// attn written unnormalized; separate rescale kernel normalizes.
// ---------------------------------------------------------------------------
__global__ __launch_bounds__(256, 3) void irpe_attn_mfma_k(
    const u16* __restrict__ qh_g, const u16* __restrict__ ql_g,
    const u16* __restrict__ kh_g, const u16* __restrict__ kl_g,
    const u16* __restrict__ vth_g, const u16* __restrict__ vtl_g,
    const float* __restrict__ tk, const float* __restrict__ tqT,
    const float* __restrict__ w_rpe_v,
    float* __restrict__ attn, float* __restrict__ s_arr, float* __restrict__ pre) {
    __shared__ u16 kvh[4096], kvl[4096];     // [64][64] swizzled (K, then vT)  16 KB
    __shared__ u16 awh[2048], awl[2048];     // e hi/lo [32][64] swizzled        8 KB
    __shared__ float tq_s[NB_ * 68];         // tq slice [49][68]             13.3 KB
    __shared__ float tks_s[32 * NB_];        // [32][49]                       6.3 KB
    __shared__ float bkt_s[32 * 50];         // [32][50]                       6.4 KB
    __shared__ float ssum_s[32];

    const int gid = blockIdx.x;
    const int xcd = gid & 7, L = gid >> 3;
    const int bh = xcd * 12 + (L >> 5);      // 12 bh per XCD, itile-inner
    const int itile = L & 31;
    const int b = bh / H_, h = bh % H_;
    const int i0 = itile * 32;
    const int yi = itile;                    // grid y of all 32 rows
    const int t = threadIdx.x;
    const int w = t >> 6, lane = t & 63;
    const int ln4 = lane >> 4, lh15 = lane & 15;
    const int mt = w & 1;
    const int jt0 = (w >> 1) * 2;
    const size_t tqbase = (size_t)bh * NB_ * 1024;
    const int arow0 = (bh << 10) + i0;

    // ---- persistent Q fragments (direct global) ----
    mfrag qAh[2], qAl[2];
#pragma unroll
    for (int ks = 0; ks < 2; ++ks) {
        const size_t qa = (((size_t)(bh << 10) + i0 + mt * 16 + lh15) << 6) + (ln4 << 3) + (ks << 5);
        qAh[ks] = *(const mfrag*)&qh_g[qa];
        qAl[ks] = *(const mfrag*)&ql_g[qa];
    }

    // ---- stage regs: K(0), tq(0) ----
    mfrag kstg[4];     // [rep*2 + hi/lo]
#pragma unroll
    for (int rep = 0; rep < 2; ++rep) {
        const int unit = rep * 256 + t;
        const int row = unit >> 3, un = unit & 7;
        const size_t gsrc = (((size_t)(bh << 10) + row) << 6) + un * 8;
        kstg[rep * 2] = *(const mfrag*)&kh_g[gsrc];
        kstg[rep * 2 + 1] = *(const mfrag*)&kl_g[gsrc];
    }
    f32x4 tqpre[4];
#pragma unroll
    for (int p = 0; p < 3; ++p) {
        const int unit = p * 256 + t, u = unit >> 4, j4 = unit & 15;
        tqpre[p] = *(const f32x4*)&tqT[tqbase + ((size_t)u << 10) + (j4 << 2)];
    }
    if (t < 16) tqpre[3] = *(const f32x4*)&tqT[tqbase + ((size_t)48 << 10) + (t << 2)];

    // ---- prologue LDS: tq_s(0), tks, bkt, ssum ----
#pragma unroll
    for (int p = 0; p < 3; ++p) {
        const int unit = p * 256 + t, u = unit >> 4, j4 = unit & 15;
        *(f32x4*)&tq_s[u * 68 + (j4 << 2)] = tqpre[p];
    }
    if (t < 16) *(f32x4*)&tq_s[48 * 68 + (t << 2)] = tqpre[3];
    {
        const size_t tkb = ((size_t)(bh << 10) + i0) * NB_;
        for (int idx = t; idx < 32 * NB_; idx += 256) tks_s[idx] = tk[tkb + idx];
    }
    for (int idx = t; idx < 1600; idx += 256) bkt_s[idx] = 0.f;
    if (t < 32) ssum_s[t] = 0.f;

    f32x4 apv[2] = {{0.f, 0.f, 0.f, 0.f}, {0.f, 0.f, 0.f, 0.f}};
    float srow[4] = {0.f, 0.f, 0.f, 0.f};

#pragma unroll 1
    for (int ch = 0; ch < 16; ++ch) {
        const int jc0 = ch << 6;

        // ---- write staged K -> kv LDS (prev PV done per loop-end barrier) ----
#pragma unroll
        for (int rep = 0; rep < 2; ++rep) {
            const int unit = rep * 256 + t;
            const int row = unit >> 3, un = unit & 7;
            const int ldso = row * 128 + ((un ^ (row & 7)) << 4);
            *(mfrag*)((char*)kvh + ldso) = kstg[rep * 2];
            *(mfrag*)((char*)kvl + ldso) = kstg[rep * 2 + 1];
        }
        __syncthreads();   // B1: K + (tq from prev iter / prologue) visible

        // ---- QK (bf16x3) ----
        f32x4 aq[2];
        __builtin_amdgcn_s_setprio(1);
#pragma unroll
        for (int ji = 0; ji < 2; ++ji) {
            const int rb = (jt0 + ji) * 16 + lh15, swb = rb & 7;
            const mfrag bh0 = *(const mfrag*)((const char*)kvh + rb * 128 + ((ln4 ^ swb) << 4));
            const mfrag bl0 = *(const mfrag*)((const char*)kvl + rb * 128 + ((ln4 ^ swb) << 4));
            const mfrag bh1 = *(const mfrag*)((const char*)kvh + rb * 128 + (((4 + ln4) ^ swb) << 4));
            const mfrag bl1 = *(const mfrag*)((const char*)kvl + rb * 128 + (((4 + ln4) ^ swb) << 4));
            f32x4 c = {0.f, 0.f, 0.f, 0.f};
            c = __builtin_amdgcn_mfma_f32_16x16x32_bf16(qAh[0], bh0, c, 0, 0, 0);
            c = __builtin_amdgcn_mfma_f32_16x16x32_bf16(qAh[0], bl0, c, 0, 0, 0);
            c = __builtin_amdgcn_mfma_f32_16x16x32_bf16(qAl[0], bh0, c, 0, 0, 0);
            c = __builtin_amdgcn_mfma_f32_16x16x32_bf16(qAh[1], bh1, c, 0, 0, 0);
            c = __builtin_amdgcn_mfma_f32_16x16x32_bf16(qAh[1], bl1, c, 0, 0, 0);
            c = __builtin_amdgcn_mfma_f32_16x16x32_bf16(qAl[1], bh1, c, 0, 0, 0);
            aq[ji] = c;
        }
        __builtin_amdgcn_s_setprio(0);

        // ---- issue next-chunk K + tq prefetch (latency hides under emit/PV) ----
        if (ch < 15) {
            const int jc1 = jc0 + 64;
#pragma unroll
            for (int rep = 0; rep < 2; ++rep) {
                const int unit = rep * 256 + t;
                const int row = unit >> 3, un = unit & 7;
                const size_t gsrc = (((size_t)(bh << 10) + jc1 + row) << 6) + un * 8;
                kstg[rep * 2] = *(const mfrag*)&kh_g[gsrc];
                kstg[rep * 2 + 1] = *(const mfrag*)&kl_g[gsrc];
            }
#pragma unroll
            for (int p = 0; p < 3; ++p) {
                const int unit = p * 256 + t, u = unit >> 4, j4 = unit & 15;
                tqpre[p] = *(const f32x4*)&tqT[tqbase + ((size_t)u << 10) + jc1 + (j4 << 2)];
            }
            if (t < 16) tqpre[3] = *(const f32x4*)&tqT[tqbase + ((size_t)48 << 10) + jc1 + (t << 2)];
        }

        // ---- V stage loads for this chunk (regs) ----
        mfrag vstg[4];
#pragma unroll
        for (int rep = 0; rep < 2; ++rep) {
            const int unit = rep * 256 + t;
            const int row = unit >> 3, un = unit & 7;
            const size_t gsrc = (((size_t)(bh * 64) + row) << 10) + jc0 + un * 8;
            vstg[rep * 2] = *(const mfrag*)&vth_g[gsrc];
            vstg[rep * 2 + 1] = *(const mfrag*)&vtl_g[gsrc];
        }
        __syncthreads();   // B2: all waves' QK reads of kv done

        // ---- bias + exp + emit ----
#pragma unroll
        for (int ji = 0; ji < 2; ++ji) {
            const int jj = jt0 + ji;
            const int yj = (ch << 1) + (jj >> 1);
            const int by = lutf(yi - yj);
            const int xj = ((jj & 1) << 4) + lh15;
            const int jl = (jj << 4) + lh15;
#pragma unroll
            for (int r = 0; r < 4; ++r) {
                const int il = mt * 16 + ln4 * 4 + r;           // i_loc == xi
                const int bij = by * 7 + lutf(il - xj);
                const float e = __expf(fmaf(aq[ji][r], SCALE_,
                                            tks_s[il * NB_ + bij] + tq_s[(48 - bij) * 68 + jl]));
                srow[r] += e;
                atomicAdd(&bkt_s[il * 50 + bij], e);
                attn[((size_t)(arow0 + il) << 10) + jc0 + jl] = e;
                const u16 eh = f2bf(e);
                const int off = il * 128 + ((jl << 1) ^ ((il & 7) << 4));
                *(u16*)((char*)awh + off) = eh;
                *(u16*)((char*)awl + off) = f2bf(e - bf2f(eh));
            }
        }

        // ---- write V stage -> kv LDS ----
#pragma unroll
        for (int rep = 0; rep < 2; ++rep) {
            const int unit = rep * 256 + t;
            const int row = unit >> 3, un = unit & 7;
            const int ldso = row * 128 + ((un ^ (row & 7)) << 4);
            *(mfrag*)((char*)kvh + ldso) = vstg[rep * 2];
            *(mfrag*)((char*)kvl + ldso) = vstg[rep * 2 + 1];
        }
        __syncthreads();   // B3: vT + aw visible

        // ---- write next tq slice (nobody reads tq_s until next emit) ----
        if (ch < 15) {
#pragma unroll
            for (int p = 0; p < 3; ++p) {
                const int unit = p * 256 + t, u = unit >> 4, j4 = unit & 15;
                *(f32x4*)&tq_s[u * 68 + (j4 << 2)] = tqpre[p];
            }
            if (t < 16) *(f32x4*)&tq_s[48 * 68 + (t << 2)] = tqpre[3];
        }

        // ---- PV (bf16x3): A from aw LDS, B from kv-as-V LDS ----
        {
            const int rowA = mt * 16 + lh15, sa = (rowA & 7) << 4;
            mfrag pah[2], pal[2];
#pragma unroll
            for (int ji = 0; ji < 2; ++ji) {
                const int ba = rowA * 128 + ((((ln4 << 4) + (ji << 6))) ^ sa);
                pah[ji] = *(const mfrag*)((const char*)awh + ba);
                pal[ji] = *(const mfrag*)((const char*)awl + ba);
            }
            __builtin_amdgcn_s_setprio(1);
#pragma unroll
            for (int di = 0; di < 2; ++di) {
                const int rv = (jt0 + di) * 16 + lh15, swv = rv & 7;
                const mfrag vh0 = *(const mfrag*)((const char*)kvh + rv * 128 + ((ln4 ^ swv) << 4));
                const mfrag vl0 = *(const mfrag*)((const char*)kvl + rv * 128 + ((ln4 ^ swv) << 4));
                const mfrag vh1 = *(const mfrag*)((const char*)kvh + rv * 128 + (((4 + ln4) ^ swv) << 4));
                const mfrag vl1 = *(const mfrag*)((const char*)kvl + rv * 128 + (((4 + ln4) ^ swv) << 4));
                f32x4 c = apv[di];
                c = __builtin_amdgcn_mfma_f32_16x16x32_bf16(pah[0], vh0, c, 0, 0, 0);
                c = __builtin_amdgcn_mfma_f32_16x16x32_bf16(pah[0], vl0, c, 0, 0, 0);
                c = __builtin_amdgcn_mfma_f32_16x16x32_bf16(pal[0], vh0, c, 0, 0, 0);
                c = __builtin_amdgcn_mfma_f32_16x16x32_bf16(pah[1], vh1, c, 0, 0, 0);
                c = __builtin_amdgcn_mfma_f32_16x16x32_bf16(pah[1], vl1, c, 0, 0, 0);
                c = __builtin_amdgcn_mfma_f32_16x16x32_bf16(pal[1], vh1, c, 0, 0, 0);
                apv[di] = c;
            }
            __builtin_amdgcn_s_setprio(0);
        }
        __syncthreads();   // B4: PV reads done (kv/aw free); tq_s(ch+1) visible
    }

    // ---- epilogue: row sums ----
#pragma unroll
    for (int r = 0; r < 4; ++r) {
        float s = srow[r];
        s += __shfl_xor(s, 1); s += __shfl_xor(s, 2);
        s += __shfl_xor(s, 4); s += __shfl_xor(s, 8);
        if (lh15 == 0) atomicAdd(&ssum_s[mt * 16 + ln4 * 4 + r], s);
    }
    __syncthreads();
    if (t < 32) s_arr[((size_t)bh << 10) + i0 + t] = ssum_s[t];

    // ---- rpe_v + normalize + write pre ----
    {
        const int d0 = (jt0 << 4) + lh15;
        f32x4 rv0 = {0.f, 0.f, 0.f, 0.f}, rv1 = {0.f, 0.f, 0.f, 0.f};
        for (int u = 0; u < NB_; ++u) {
            const float wv0 = w_rpe_v[u * 64 + d0];
            const float wv1 = w_rpe_v[u * 64 + 16 + d0];
#pragma unroll
            for (int r = 0; r < 4; ++r) {
                const float bv = bkt_s[(mt * 16 + ln4 * 4 + r) * 50 + u];
                rv0[r] += bv * wv0;
                rv1[r] += bv * wv1;
            }
        }
#pragma unroll
        for (int r = 0; r < 4; ++r) {
            const int il = mt * 16 + ln4 * 4 + r;
            const float inv = 1.0f / ssum_s[il];
            const size_t ob = ((size_t)(b * N_ + i0 + il)) * C_ + h * HD_;
            pre[ob + d0] = (apv[0][r] + rv0[r]) * inv;
            pre[ob + 16 + d0] = (apv[1][r] + rv1[r]) * inv;
        }
    }
}

// ---------------------------------------------------------------------------
// K4: normalize attn rows by 1/rowsum (separate kernel: keeps L2 clean for main)
// ---------------------------------------------------------------------------
__global__ void irpe_rescale_k(float* __restrict__ attn, const float* __restrict__ s_arr) {
    const int bh = blockIdx.y;
    const int i = blockIdx.x * 4 + (threadIdx.x >> 6);
    const int lane = threadIdx.x & 63;
    const float inv = 1.0f / s_arr[((size_t)bh << 10) + i];
    float4* row = (float4*)&attn[((((size_t)bh << 10) + i) << 10)];
#pragma unroll
    for (int qd = 0; qd < 4; ++qd) {
        float4 x = row[lane + qd * 64];
        x.x *= inv; x.y *= inv; x.z *= inv; x.w *= inv;
        row[lane + qd * 64] = x;
    }
}

// ---------------------------------------------------------------------------
// K5: projection GEMM (f32): out[m,n] = pre[m,:] . proj_w[n,:] + bias[n]
// ---------------------------------------------------------------------------
__global__ void irpe_proj_gemm_k(const float* __restrict__ A, const float* __restrict__ Bw,
                                 const float* __restrict__ bias, float* __restrict__ Cout) {
    const int bm = blockIdx.x * 64, bn = blockIdx.y * 64;
    __shared__ float As[16][64];
    __shared__ float Bs[16][64];
    const int t = threadIdx.x;
    const int lr = t >> 2;
    const int lc = (t & 3) * 4;
    const int tx = t & 15, ty = t >> 4;
    float acc[4][4] = {{0.f}};

    for (int kt = 0; kt < C_; kt += 16) {
        const float4 av = *(const float4*)&A[(size_t)(bm + lr) * C_ + kt + lc];
        const float4 bv = *(const float4*)&Bw[(size_t)(bn + lr) * C_ + kt + lc];
        As[lc + 0][lr] = av.x; As[lc + 1][lr] = av.y; As[lc + 2][lr] = av.z; As[lc + 3][lr] = av.w;
        Bs[lc + 0][lr] = bv.x; Bs[lc + 1][lr] = bv.y; Bs[lc + 2][lr] = bv.z; Bs[lc + 3][lr] = bv.w;
        __syncthreads();
#pragma unroll
        for (int kk = 0; kk < 16; ++kk) {
            const float4 a = *(const float4*)&As[kk][ty * 4];
            const float4 b = *(const float4*)&Bs[kk][tx * 4];
            const float ar[4] = {a.x, a.y, a.z, a.w};
            const float br[4] = {b.x, b.y, b.z, b.w};
#pragma unroll
            for (int r = 0; r < 4; ++r)
#pragma unroll
                for (int c = 0; c < 4; ++c) acc[r][c] = fmaf(ar[r], br[c], acc[r][c]);
        }
        __syncthreads();
    }
#pragma unroll
    for (int r = 0; r < 4; ++r) {
        const int rowi = bm + ty * 4 + r;
#pragma unroll
        for (int c = 0; c < 4; ++c)
            Cout[(size_t)rowi * C_ + bn + tx * 4 + c] = acc[r][c] + bias[bn + tx * 4 + c];
    }
}

// ---------------------------------------------------------------------------
extern "C" void kernel_launch(void* const* d_in, const int* in_sizes, int n_in,
                              void* d_out, int out_size, void* d_ws, size_t ws_size,
                              hipStream_t stream) {
    const float* q       = (const float*)d_in[0];
    const float* k       = (const float*)d_in[1];
    const float* v       = (const float*)d_in[2];
    const float* w_rpe_q = (const float*)d_in[3];
    const float* w_rpe_k = (const float*)d_in[4];
    const float* w_rpe_v = (const float*)d_in[5];
    const float* proj_w  = (const float*)d_in[6];
    const float* proj_b  = (const float*)d_in[7];

    float* out  = (float*)d_out;               // [B,N,C]
    float* attn = out + (size_t)B_ * N_ * C_;  // [B,H,N,N]

    char* ws = (char*)d_ws;
    float* tk    = (float*)ws; ws += (size_t)BH_ * N_ * NB_ * 4;
    float* tqT   = (float*)ws; ws += (size_t)BH_ * NB_ * N_ * 4;
    float* pre   = (float*)ws; ws += (size_t)B_ * N_ * C_ * 4;
    float* s_arr = (float*)ws; ws += (size_t)BH_ * N_ * 4;
    u16* qh  = (u16*)ws; ws += (size_t)BH_ * N_ * 64 * 2;
    u16* ql  = (u16*)ws; ws += (size_t)BH_ * N_ * 64 * 2;
    u16* kh  = (u16*)ws; ws += (size_t)BH_ * N_ * 64 * 2;
    u16* kl  = (u16*)ws; ws += (size_t)BH_ * N_ * 64 * 2;
    u16* vth = (u16*)ws; ws += (size_t)BH_ * 64 * N_ * 2;
    u16* vtl = (u16*)ws; ws += (size_t)BH_ * 64 * N_ * 2;

    irpe_split_qk_k<<<6144, 256, 0, stream>>>(q, k, qh, ql, kh, kl);
    irpe_vt_k<<<dim3(16, BH_), 256, 0, stream>>>(v, vth, vtl);
    irpe_rpe_tables_k<<<dim3(N_ / 4, BH_), 256, 0, stream>>>(q, k, w_rpe_q, w_rpe_k, tk, tqT);

    irpe_attn_mfma_k<<<BH_ * (N_ / 32), 256, 0, stream>>>(
        qh, ql, kh, kl, vth, vtl, tk, tqT, w_rpe_v, attn, s_arr, pre);

    irpe_rescale_k<<<dim3(N_ / 4, BH_), 256, 0, stream>>>(attn, s_arr);
    irpe_proj_gemm_k<<<dim3((B_ * N_) / 64, C_ / 64), 256, 0, stream>>>(pre, proj_w, proj_b, out);
}

// Round 6
// 784.113 us; speedup vs baseline: 1.8797x; 1.6164x over previous
//
#include <hip/hip_runtime.h>

#define B_ 8
#define N_ 1024
#define C_ 768
#define H_ 12
#define HD_ 64
#define NB_ 49
#define BH_ 96
#define SCALE_ 0.125f

typedef unsigned int u32;
typedef unsigned short u16;
typedef __attribute__((ext_vector_type(8))) short mfrag;   // 8 bf16 (4 VGPRs)
typedef __attribute__((ext_vector_type(4))) float f32x4;

__device__ __forceinline__ u16 f2bf(float x) {             // f32 -> bf16 (RNE)
    u32 u = __float_as_uint(x);
    u32 r = u + 0x7FFFu + ((u >> 16) & 1u);
    return (u16)(r >> 16);
}
__device__ __forceinline__ float bf2f(u16 h) { return __uint_as_float(((u32)h) << 16); }

// iRPE piecewise bucket (closed form for ALPHA=1.9, BETA=3.8, GAMMA=15.2):
// |d|: 0->0, 1->1, 2,3->2, >=4->3 ; bucket = 3 + sign(d)*g  (in [0,6])
__device__ __forceinline__ int lutf(int d) {
    int a = d < 0 ? -d : d;
    int gg = (a < 2 ? a : 2) + (a >= 4 ? 1 : 0);
    return d < 0 ? 3 - gg : 3 + gg;
}

// ---------------------------------------------------------------------------
// K0a: split q,k into per-head bf16 hi/lo buffers [bh][n][64]
// ---------------------------------------------------------------------------
__global__ void irpe_split_qk_k(const float* __restrict__ q, const float* __restrict__ k,
                                u16* __restrict__ qh, u16* __restrict__ ql,
                                u16* __restrict__ kh, u16* __restrict__ kl) {
    const int tid = blockIdx.x * 256 + threadIdx.x;
    const int o = tid * 4;
    const int bh = o >> 16, rem = o & 65535;
    const int n = rem >> 6, d = rem & 63;
    const int b = bh / H_, h = bh % H_;
    const size_t src = ((size_t)(b * N_ + n)) * C_ + h * HD_ + d;
    const float4 qv = *(const float4*)&q[src];
    const float4 kv = *(const float4*)&k[src];
    ushort4 a, c;
    a = make_ushort4(f2bf(qv.x), f2bf(qv.y), f2bf(qv.z), f2bf(qv.w));
    c = make_ushort4(f2bf(qv.x - bf2f(a.x)), f2bf(qv.y - bf2f(a.y)),
                     f2bf(qv.z - bf2f(a.z)), f2bf(qv.w - bf2f(a.w)));
    *(ushort4*)&qh[o] = a;
    *(ushort4*)&ql[o] = c;
    a = make_ushort4(f2bf(kv.x), f2bf(kv.y), f2bf(kv.z), f2bf(kv.w));
    c = make_ushort4(f2bf(kv.x - bf2f(a.x)), f2bf(kv.y - bf2f(a.y)),
                     f2bf(kv.z - bf2f(a.z)), f2bf(kv.w - bf2f(a.w)));
    *(ushort4*)&kh[o] = a;
    *(ushort4*)&kl[o] = c;
}

// ---------------------------------------------------------------------------
// K0b: v -> transposed bf16 hi/lo [bh][64(d)][1024(j)]
// ---------------------------------------------------------------------------
__global__ void irpe_vt_k(const float* __restrict__ v,
                          u16* __restrict__ vth, u16* __restrict__ vtl) {
    __shared__ float tile[64][65];
    const int bh = blockIdx.y, jc0 = blockIdx.x * 64;
    const int b = bh / H_, h = bh % H_;
    const int t = threadIdx.x;
#pragma unroll
    for (int rep = 0; rep < 4; ++rep) {
        const int fl = rep * 256 + t;
        const int jr = fl >> 4, c4 = (fl & 15) * 4;
        const float4 x = *(const float4*)&v[((size_t)(b * N_ + jc0 + jr)) * C_ + h * HD_ + c4];
        tile[jr][c4] = x.x; tile[jr][c4 + 1] = x.y; tile[jr][c4 + 2] = x.z; tile[jr][c4 + 3] = x.w;
    }
    __syncthreads();
    const int d = t >> 2, jq = (t & 3) * 16;
    u32 ph[8], pl[8];
#pragma unroll
    for (int jj = 0; jj < 8; ++jj) {
        const float x0 = tile[jq + jj * 2][d], x1 = tile[jq + jj * 2 + 1][d];
        const u16 h0 = f2bf(x0), h1 = f2bf(x1);
        const float r0 = x0 - bf2f(h0), r1 = x1 - bf2f(h1);
        ph[jj] = (u32)h0 | ((u32)h1 << 16);
        pl[jj] = (u32)f2bf(r0) | ((u32)f2bf(r1) << 16);
    }
    const size_t dst = (((size_t)bh * 64 + d) << 10) + jc0 + jq;
    *(uint4*)&vth[dst] = make_uint4(ph[0], ph[1], ph[2], ph[3]);
    *(uint4*)&vth[dst + 8] = make_uint4(ph[4], ph[5], ph[6], ph[7]);
    *(uint4*)&vtl[dst] = make_uint4(pl[0], pl[1], pl[2], pl[3]);
    *(uint4*)&vtl[dst + 8] = make_uint4(pl[4], pl[5], pl[6], pl[7]);
}

// ---------------------------------------------------------------------------
// K2: RPE tables. tk[bh][i][49] ; tqT[bh][49][1024] (pre-scaled)
// ---------------------------------------------------------------------------
__global__ void irpe_rpe_tables_k(const float* __restrict__ q, const float* __restrict__ k,
                                  const float* __restrict__ w_rpe_q, const float* __restrict__ w_rpe_k,
                                  float* __restrict__ tk, float* __restrict__ tqT) {
    const int bh = blockIdx.y, b = bh / H_, h = bh % H_;
    const int row0 = blockIdx.x * 4;
    __shared__ float qs[4][HD_], ks[4][HD_];
    const int t = threadIdx.x;
    {
        const int r = t >> 6, d = t & 63;
        const size_t gi = ((size_t)(b * N_ + row0 + r)) * C_ + h * HD_ + d;
        qs[r][d] = q[gi];
        ks[r][d] = k[gi];
    }
    __syncthreads();
    if (t < 4 * NB_) {
        const int r = t / NB_, u = t - r * NB_;
        float dk = 0.f, dq = 0.f;
#pragma unroll
        for (int d = 0; d < HD_; ++d) {
            dk = fmaf(qs[r][d], w_rpe_k[d * NB_ + u], dk);
            dq = fmaf(ks[r][d], w_rpe_q[d * NB_ + u], dq);
        }
        tk[((size_t)bh * N_ + row0 + r) * NB_ + u] = dk;
        tqT[(((size_t)bh * NB_ + u) << 10) + row0 + r] = dq * SCALE_;
    }
}

// ---------------------------------------------------------------------------
// K_main: single-sweep fused attention, bf16x3 MFMA, wave-local P.
// Block = (bh, 64 i-rows), XCD-pinned. 4 waves, wave w owns rows w*16..w*16+15
// and computes ALL 4 j-tiles for them -> P (aw) write/read is wave-local
// (lgkmcnt only, no barrier). Separate K and V LDS buffers -> 2 barriers/chunk:
//   stage K/V/tq -> B1 -> QK -> prefetch(ch+1) -> emit -> PV -> B2
// Prefetch loads & attn stores drain at B2 after a full compute phase.
// Buckets moved OUT (rescale kernel). attn written unnormalized.
// ---------------------------------------------------------------------------
__global__ __launch_bounds__(256, 2) void irpe_attn_mfma_k(
    const u16* __restrict__ qh_g, const u16* __restrict__ ql_g,
    const u16* __restrict__ kh_g, const u16* __restrict__ kl_g,
    const u16* __restrict__ vth_g, const u16* __restrict__ vtl_g,
    const float* __restrict__ tk, const float* __restrict__ tqT,
    float* __restrict__ attn, float* __restrict__ s_arr, float* __restrict__ pre) {
    __shared__ u16 kAh[4096], kAl[4096];     // K  [64 j][64 d] swizzled  16 KB
    __shared__ u16 vAh[4096], vAl[4096];     // vT [64 d][64 j] swizzled  16 KB
    __shared__ u16 awh[4096], awl[4096];     // P  [64 i][64 j] swizzled  16 KB
    __shared__ float tq_s[NB_ * 68];         // [49][68]                13.3 KB
    __shared__ float tks_s[64 * NB_];        // [64][49]                12.5 KB

    const int gid = blockIdx.x;
    const int xcd = gid & 7, L = gid >> 3;
    const int bh = xcd * 12 + (L >> 4);      // 12 bh per XCD, itile-inner
    const int itile = L & 15;
    const int b = bh / H_, h = bh % H_;
    const int i0 = itile * 64;
    const int t = threadIdx.x;
    const int w = t >> 6, lane = t & 63;
    const int ln4 = lane >> 4, lh15 = lane & 15;
    const int yi = itile * 2 + (w >> 1);     // wave-uniform grid-y of its rows
    const size_t tqbase = (size_t)bh * NB_ * 1024;
    const int arow0 = (bh << 10) + i0;

    // ---- persistent Q fragments (wave rows w*16+lh15) ----
    mfrag qAh[2], qAl[2];
#pragma unroll
    for (int ks = 0; ks < 2; ++ks) {
        const size_t qa = (((size_t)(bh << 10) + i0 + w * 16 + lh15) << 6) + (ln4 << 3) + (ks << 5);
        qAh[ks] = *(const mfrag*)&qh_g[qa];
        qAl[ks] = *(const mfrag*)&ql_g[qa];
    }

    // ---- chunk-invariant bucket-x: bxp[jhalf][r] = lutf(xi - xj) ----
    int bxp[2][4];
#pragma unroll
    for (int jh = 0; jh < 2; ++jh)
#pragma unroll
        for (int r = 0; r < 4; ++r) {
            const int xi = (w & 1) * 16 + ln4 * 4 + r;
            bxp[jh][r] = lutf(xi - (jh * 16 + lh15));
        }

    // ---- prefetch regs for chunk 0 ----
    mfrag kstg[4], vstg[4];
#pragma unroll
    for (int rep = 0; rep < 2; ++rep) {
        const int unit = rep * 256 + t;
        const int row = unit >> 3, un = unit & 7;
        const size_t ka = (((size_t)(bh << 10) + row) << 6) + un * 8;
        kstg[rep * 2] = *(const mfrag*)&kh_g[ka];
        kstg[rep * 2 + 1] = *(const mfrag*)&kl_g[ka];
        const size_t va = (((size_t)(bh * 64) + row) << 10) + un * 8;
        vstg[rep * 2] = *(const mfrag*)&vth_g[va];
        vstg[rep * 2 + 1] = *(const mfrag*)&vtl_g[va];
    }
    f32x4 tqpre[4];
#pragma unroll
    for (int p = 0; p < 3; ++p) {
        const int unit = p * 256 + t, u = unit >> 4, j4 = unit & 15;
        tqpre[p] = *(const f32x4*)&tqT[tqbase + ((size_t)u << 10) + (j4 << 2)];
    }
    if (t < 16) tqpre[3] = *(const f32x4*)&tqT[tqbase + ((size_t)48 << 10) + (t << 2)];

    // ---- tks -> LDS (once) ----
    {
        const size_t tkb = ((size_t)(bh << 10) + i0) * NB_;
        for (int idx = t; idx < 64 * NB_; idx += 256) tks_s[idx] = tk[tkb + idx];
    }

    f32x4 apv[4] = {{0.f, 0.f, 0.f, 0.f}, {0.f, 0.f, 0.f, 0.f},
                    {0.f, 0.f, 0.f, 0.f}, {0.f, 0.f, 0.f, 0.f}};
    float srow[4] = {0.f, 0.f, 0.f, 0.f};

#pragma unroll 1
    for (int ch = 0; ch < 16; ++ch) {
        const int jc0 = ch << 6;

        // ---- stage K/V/tq from regs -> LDS ----
#pragma unroll
        for (int rep = 0; rep < 2; ++rep) {
            const int unit = rep * 256 + t;
            const int row = unit >> 3, un = unit & 7;
            const int ldso = row * 128 + ((un ^ (row & 7)) << 4);
            *(mfrag*)((char*)kAh + ldso) = kstg[rep * 2];
            *(mfrag*)((char*)kAl + ldso) = kstg[rep * 2 + 1];
            *(mfrag*)((char*)vAh + ldso) = vstg[rep * 2];
            *(mfrag*)((char*)vAl + ldso) = vstg[rep * 2 + 1];
        }
#pragma unroll
        for (int p = 0; p < 3; ++p) {
            const int unit = p * 256 + t, u = unit >> 4, j4 = unit & 15;
            *(f32x4*)&tq_s[u * 68 + (j4 << 2)] = tqpre[p];
        }
        if (t < 16) *(f32x4*)&tq_s[48 * 68 + (t << 2)] = tqpre[3];
        __syncthreads();   // B1: stage visible (loads were issued a chunk ago)

        // ---- QK (bf16x3): all 4 j-tiles for this wave's 16 rows ----
        f32x4 aq[4];
        __builtin_amdgcn_s_setprio(1);
#pragma unroll
        for (int ji = 0; ji < 4; ++ji) {
            const int rb = ji * 16 + lh15, swb = rb & 7;
            const mfrag bh0 = *(const mfrag*)((const char*)kAh + rb * 128 + ((ln4 ^ swb) << 4));
            const mfrag bl0 = *(const mfrag*)((const char*)kAl + rb * 128 + ((ln4 ^ swb) << 4));
            const mfrag bh1 = *(const mfrag*)((const char*)kAh + rb * 128 + (((4 + ln4) ^ swb) << 4));
            const mfrag bl1 = *(const mfrag*)((const char*)kAl + rb * 128 + (((4 + ln4) ^ swb) << 4));
            f32x4 c = {0.f, 0.f, 0.f, 0.f};
            c = __builtin_amdgcn_mfma_f32_16x16x32_bf16(qAh[0], bh0, c, 0, 0, 0);
            c = __builtin_amdgcn_mfma_f32_16x16x32_bf16(qAh[0], bl0, c, 0, 0, 0);
            c = __builtin_amdgcn_mfma_f32_16x16x32_bf16(qAl[0], bh0, c, 0, 0, 0);
            c = __builtin_amdgcn_mfma_f32_16x16x32_bf16(qAh[1], bh1, c, 0, 0, 0);
            c = __builtin_amdgcn_mfma_f32_16x16x32_bf16(qAh[1], bl1, c, 0, 0, 0);
            c = __builtin_amdgcn_mfma_f32_16x16x32_bf16(qAl[1], bh1, c, 0, 0, 0);
            aq[ji] = c;
        }
        __builtin_amdgcn_s_setprio(0);

        // ---- issue prefetch for ch+1 (drains at B2, after full compute) ----
        if (ch < 15) {
            const int jc1 = jc0 + 64;
#pragma unroll
            for (int rep = 0; rep < 2; ++rep) {
                const int unit = rep * 256 + t;
                const int row = unit >> 3, un = unit & 7;
                const size_t ka = (((size_t)(bh << 10) + jc1 + row) << 6) + un * 8;
                kstg[rep * 2] = *(const mfrag*)&kh_g[ka];
                kstg[rep * 2 + 1] = *(const mfrag*)&kl_g[ka];
                const size_t va = (((size_t)(bh * 64) + row) << 10) + jc1 + un * 8;
                vstg[rep * 2] = *(const mfrag*)&vth_g[va];
                vstg[rep * 2 + 1] = *(const mfrag*)&vtl_g[va];
            }
#pragma unroll
            for (int p = 0; p < 3; ++p) {
                const int unit = p * 256 + t, u = unit >> 4, j4 = unit & 15;
                tqpre[p] = *(const f32x4*)&tqT[tqbase + ((size_t)u << 10) + jc1 + (j4 << 2)];
            }
            if (t < 16) tqpre[3] = *(const f32x4*)&tqT[tqbase + ((size_t)48 << 10) + jc1 + (t << 2)];
        }

        // ---- bias + exp + emit (wave-local aw rows) ----
#pragma unroll
        for (int ji = 0; ji < 4; ++ji) {
            const int yj = (ch << 1) + (ji >> 1);
            const int by7 = 7 * lutf(yi - yj);
            const int jl = ji * 16 + lh15;
#pragma unroll
            for (int r = 0; r < 4; ++r) {
                const int il = w * 16 + ln4 * 4 + r;
                const int bij = by7 + bxp[ji & 1][r];
                const float e = __expf(fmaf(aq[ji][r], SCALE_,
                                            tks_s[il * NB_ + bij] + tq_s[(48 - bij) * 68 + jl]));
                srow[r] += e;
                attn[((size_t)(arow0 + il) << 10) + jc0 + jl] = e;
                const u16 eh = f2bf(e);
                const int off = il * 128 + ((jl << 1) ^ ((il & 7) << 4));
                *(u16*)((char*)awh + off) = eh;
                *(u16*)((char*)awl + off) = f2bf(e - bf2f(eh));
            }
        }
        // wave-local aw: compiler inserts lgkmcnt wait before PV reads

        // ---- PV (bf16x3): P from own aw rows, V from vA LDS ----
        {
            const int rowA = w * 16 + lh15, sa = (rowA & 7) << 4;
            mfrag pah[2], pal[2];
#pragma unroll
            for (int ks = 0; ks < 2; ++ks) {
                const int ba = rowA * 128 + ((((ln4 << 4) + (ks << 6))) ^ sa);
                pah[ks] = *(const mfrag*)((const char*)awh + ba);
                pal[ks] = *(const mfrag*)((const char*)awl + ba);
            }
            __builtin_amdgcn_s_setprio(1);
#pragma unroll
            for (int di = 0; di < 4; ++di) {
                const int rv = di * 16 + lh15, swv = rv & 7;
                f32x4 c = apv[di];
#pragma unroll
                for (int ks = 0; ks < 2; ++ks) {
                    const mfrag vh = *(const mfrag*)((const char*)vAh + rv * 128 + (((ks * 4 + ln4) ^ swv) << 4));
                    const mfrag vl = *(const mfrag*)((const char*)vAl + rv * 128 + (((ks * 4 + ln4) ^ swv) << 4));
                    c = __builtin_amdgcn_mfma_f32_16x16x32_bf16(pah[ks], vh, c, 0, 0, 0);
                    c = __builtin_amdgcn_mfma_f32_16x16x32_bf16(pah[ks], vl, c, 0, 0, 0);
                    c = __builtin_amdgcn_mfma_f32_16x16x32_bf16(pal[ks], vh, c, 0, 0, 0);
                }
                apv[di] = c;
            }
            __builtin_amdgcn_s_setprio(0);
        }
        __syncthreads();   // B2: all LDS reads done; prefetch/stores drained
    }

    // ---- epilogue: row sums (butterfly over 16 lanes sharing a row) ----
    float inv[4];
#pragma unroll
    for (int r = 0; r < 4; ++r) {
        float s = srow[r];
        s += __shfl_xor(s, 1); s += __shfl_xor(s, 2);
        s += __shfl_xor(s, 4); s += __shfl_xor(s, 8);
        inv[r] = 1.0f / s;
        if (lh15 == 0) s_arr[((size_t)bh << 10) + i0 + w * 16 + ln4 * 4 + r] = s;
    }

    // ---- normalize + write pre (no rpe_v here; added later from bs) ----
#pragma unroll
    for (int di = 0; di < 4; ++di) {
        const int d = di * 16 + lh15;
#pragma unroll
        for (int r = 0; r < 4; ++r) {
            const int i = i0 + w * 16 + ln4 * 4 + r;
            pre[((size_t)(b * N_ + i)) * C_ + h * HD_ + d] = apv[di][r] * inv[r];
        }
    }
}

// ---------------------------------------------------------------------------
// K4: rescale attn rows by 1/rowsum AND compute bucket sums bs[bh][i][49].
// Stage 1: R[r][yj][bx] partials (run-combined, <=2-way LDS atomic conflicts).
// Stage 2: bs[u=7*by+bx] = sum over yj with lutf(yi-yj)==by.
// ---------------------------------------------------------------------------
__global__ void irpe_rescale_bucket_k(float* __restrict__ attn, const float* __restrict__ s_arr,
                                      float* __restrict__ bs) {
    __shared__ float R[4][32][8];    // 4 KB
    __shared__ float inv_s[4];
    const int bh = blockIdx.y;
    const int i0 = blockIdx.x * 4;
    const int t = threadIdx.x;
    const int r = t >> 6, lane = t & 63;
    const int i = i0 + r, xi = i & 31;
    const float inv = 1.0f / s_arr[((size_t)bh << 10) + i];
    if (lane == 0) inv_s[r] = inv;
    for (int idx = t; idx < 4 * 32 * 8; idx += 256) ((float*)R)[idx] = 0.f;
    __syncthreads();

    const int j0 = lane * 16;
    const int yj = j0 >> 5;
    float4* rowp = (float4*)&attn[((size_t)((bh << 10) + i)) << 10];
    float4 xv0 = rowp[(j0 >> 2) + 0], xv1 = rowp[(j0 >> 2) + 1];
    float4 xv2 = rowp[(j0 >> 2) + 2], xv3 = rowp[(j0 >> 2) + 3];

    float acc = 0.f;
    int cur = lutf(xi - (j0 & 31));
#define STEP_(val, xjc) { const int bx_ = lutf(xi - (xjc));                         \
        if (bx_ != cur) { atomicAdd(&R[r][yj][cur], acc); acc = 0.f; cur = bx_; }   \
        acc += (val); }
    const int xb = j0 & 31;
    STEP_(xv0.x, xb + 0)  STEP_(xv0.y, xb + 1)  STEP_(xv0.z, xb + 2)  STEP_(xv0.w, xb + 3)
    STEP_(xv1.x, xb + 4)  STEP_(xv1.y, xb + 5)  STEP_(xv1.z, xb + 6)  STEP_(xv1.w, xb + 7)
    STEP_(xv2.x, xb + 8)  STEP_(xv2.y, xb + 9)  STEP_(xv2.z, xb + 10) STEP_(xv2.w, xb + 11)
    STEP_(xv3.x, xb + 12) STEP_(xv3.y, xb + 13) STEP_(xv3.z, xb + 14) STEP_(xv3.w, xb + 15)
    atomicAdd(&R[r][yj][cur], acc);
#undef STEP_

    xv0.x *= inv; xv0.y *= inv; xv0.z *= inv; xv0.w *= inv;
    xv1.x *= inv; xv1.y *= inv; xv1.z *= inv; xv1.w *= inv;
    xv2.x *= inv; xv2.y *= inv; xv2.z *= inv; xv2.w *= inv;
    xv3.x *= inv; xv3.y *= inv; xv3.z *= inv; xv3.w *= inv;
    rowp[(j0 >> 2) + 0] = xv0; rowp[(j0 >> 2) + 1] = xv1;
    rowp[(j0 >> 2) + 2] = xv2; rowp[(j0 >> 2) + 3] = xv3;
    __syncthreads();

    if (t < 4 * NB_) {
        const int rr = t / NB_, u = t - rr * NB_;
        const int by = u / 7, bx = u - by * 7;
        const int yi2 = (i0 + rr) >> 5;
        float s = 0.f;
#pragma unroll
        for (int yj2 = 0; yj2 < 32; ++yj2)
            if (lutf(yi2 - yj2) == by) s += R[rr][yj2][bx];
        bs[((size_t)((bh << 10) + i0 + rr)) * NB_ + u] = s * inv_s[rr];
    }
}

// ---------------------------------------------------------------------------
// K4b: pre += bs @ w_rpe_v   (tiny)
// ---------------------------------------------------------------------------
__global__ void irpe_addpre_k(const float* __restrict__ bs, const float* __restrict__ w_rpe_v,
                              float* __restrict__ pre) {
    __shared__ float wv[NB_ * 64];     // 12.5 KB
    __shared__ float bss[16 * 52];
    const int bh = blockIdx.y, b = bh / H_, h = bh % H_;
    const int i0 = blockIdx.x * 16;
    const int t = threadIdx.x;
    for (int idx = t; idx < NB_ * 64; idx += 256) wv[idx] = w_rpe_v[idx];
    for (int idx = t; idx < 16 * NB_; idx += 256) {
        const int il = idx / NB_, u = idx - il * NB_;
        bss[il * 52 + u] = bs[((size_t)((bh << 10) + i0 + il)) * NB_ + u];
    }
    __syncthreads();
    const int il = t >> 4, d4 = (t & 15) * 4;
    f32x4 acc = {0.f, 0.f, 0.f, 0.f};
    for (int u = 0; u < NB_; ++u) {
        const float bv = bss[il * 52 + u];
        const f32x4 wvv = *(const f32x4*)&wv[u * 64 + d4];
        acc += bv * wvv;
    }
    float* p = &pre[((size_t)(b * N_ + i0 + il)) * C_ + h * HD_ + d4];
    f32x4 old = *(const f32x4*)p;
    *(f32x4*)p = old + acc;
}

// ---------------------------------------------------------------------------
// K5: projection GEMM (f32): out[m,n] = pre[m,:] . proj_w[n,:] + bias[n]
// ---------------------------------------------------------------------------
__global__ void irpe_proj_gemm_k(const float* __restrict__ A, const float* __restrict__ Bw,
                                 const float* __restrict__ bias, float* __restrict__ Cout) {
    const int bm = blockIdx.x * 64, bn = blockIdx.y * 64;
    __shared__ float As[16][64];
    __shared__ float Bs[16][64];
    const int t = threadIdx.x;
    const int lr = t >> 2;
    const int lc = (t & 3) * 4;
    const int tx = t & 15, ty = t >> 4;
    float acc[4][4] = {{0.f}};

    for (int kt = 0; kt < C_; kt += 16) {
        const float4 av = *(const float4*)&A[(size_t)(bm + lr) * C_ + kt + lc];
        const float4 bv = *(const float4*)&Bw[(size_t)(bn + lr) * C_ + kt + lc];
        As[lc + 0][lr] = av.x; As[lc + 1][lr] = av.y; As[lc + 2][lr] = av.z; As[lc + 3][lr] = av.w;
        Bs[lc + 0][lr] = bv.x; Bs[lc + 1][lr] = bv.y; Bs[lc + 2][lr] = bv.z; Bs[lc + 3][lr] = bv.w;
        __syncthreads();
#pragma unroll
        for (int kk = 0; kk < 16; ++kk) {
            const float4 a = *(const float4*)&As[kk][ty * 4];
            const float4 b = *(const float4*)&Bs[kk][tx * 4];
            const float ar[4] = {a.x, a.y, a.z, a.w};
            const float br[4] = {b.x, b.y, b.z, b.w};
#pragma unroll
            for (int r = 0; r < 4; ++r)
#pragma unroll
                for (int c = 0; c < 4; ++c) acc[r][c] = fmaf(ar[r], br[c], acc[r][c]);
        }
        __syncthreads();
    }
#pragma unroll
    for (int r = 0; r < 4; ++r) {
        const int rowi = bm + ty * 4 + r;
#pragma unroll
        for (int c = 0; c < 4; ++c)
            Cout[(size_t)rowi * C_ + bn + tx * 4 + c] = acc[r][c] + bias[bn + tx * 4 + c];
    }
}

// ---------------------------------------------------------------------------
extern "C" void kernel_launch(void* const* d_in, const int* in_sizes, int n_in,
                              void* d_out, int out_size, void* d_ws, size_t ws_size,
                              hipStream_t stream) {
    const float* q       = (const float*)d_in[0];
    const float* k       = (const float*)d_in[1];
    const float* v       = (const float*)d_in[2];
    const float* w_rpe_q = (const float*)d_in[3];
    const float* w_rpe_k = (const float*)d_in[4];
    const float* w_rpe_v = (const float*)d_in[5];
    const float* proj_w  = (const float*)d_in[6];
    const float* proj_b  = (const float*)d_in[7];

    float* out  = (float*)d_out;               // [B,N,C]
    float* attn = out + (size_t)B_ * N_ * C_;  // [B,H,N,N]

    char* ws = (char*)d_ws;
    float* tk    = (float*)ws; ws += (size_t)BH_ * N_ * NB_ * 4;
    float* tqT   = (float*)ws; ws += (size_t)BH_ * NB_ * N_ * 4;
    float* pre   = (float*)ws; ws += (size_t)B_ * N_ * C_ * 4;
    float* s_arr = (float*)ws; ws += (size_t)BH_ * N_ * 4;
    float* bs    = (float*)ws; ws += (size_t)BH_ * N_ * NB_ * 4;
    u16* qh  = (u16*)ws; ws += (size_t)BH_ * N_ * 64 * 2;
    u16* ql  = (u16*)ws; ws += (size_t)BH_ * N_ * 64 * 2;
    u16* kh  = (u16*)ws; ws += (size_t)BH_ * N_ * 64 * 2;
    u16* kl  = (u16*)ws; ws += (size_t)BH_ * N_ * 64 * 2;
    u16* vth = (u16*)ws; ws += (size_t)BH_ * 64 * N_ * 2;
    u16* vtl = (u16*)ws; ws += (size_t)BH_ * 64 * N_ * 2;

    irpe_split_qk_k<<<6144, 256, 0, stream>>>(q, k, qh, ql, kh, kl);
    irpe_vt_k<<<dim3(16, BH_), 256, 0, stream>>>(v, vth, vtl);
    irpe_rpe_tables_k<<<dim3(N_ / 4, BH_), 256, 0, stream>>>(q, k, w_rpe_q, w_rpe_k, tk, tqT);

    irpe_attn_mfma_k<<<BH_ * (N_ / 64), 256, 0, stream>>>(
        qh, ql, kh, kl, vth, vtl, tk, tqT, attn, s_arr, pre);

    irpe_rescale_bucket_k<<<dim3(N_ / 4, BH_), 256, 0, stream>>>(attn, s_arr, bs);
    irpe_addpre_k<<<dim3(N_ / 16, BH_), 256, 0, stream>>>(bs, w_rpe_v, pre);
    irpe_proj_gemm_k<<<dim3((B_ * N_) / 64, C_ / 64), 256, 0, stream>>>(pre, proj_w, proj_b, out);
}

// Round 7
// 762.982 us; speedup vs baseline: 1.9318x; 1.0277x over previous
//
#include <hip/hip_runtime.h>

#define B_ 8
#define N_ 1024
#define C_ 768
#define H_ 12
#define HD_ 64
#define NB_ 49
#define BH_ 96
#define SCALE_ 0.125f

typedef unsigned int u32;
typedef unsigned short u16;
typedef __attribute__((ext_vector_type(8))) short mfrag;   // 8 bf16 (4 VGPRs)
typedef __attribute__((ext_vector_type(4))) float f32x4;

__device__ __forceinline__ u16 f2bf(float x) {             // f32 -> bf16 (RNE)
    u32 u = __float_as_uint(x);
    u32 r = u + 0x7FFFu + ((u >> 16) & 1u);
    return (u16)(r >> 16);
}
__device__ __forceinline__ float bf2f(u16 h) { return __uint_as_float(((u32)h) << 16); }

// iRPE piecewise bucket (closed form for ALPHA=1.9, BETA=3.8, GAMMA=15.2):
// |d|: 0->0, 1->1, 2,3->2, >=4->3 ; bucket = 3 + sign(d)*g  (in [0,6])
__device__ __forceinline__ int lutf(int d) {
    int a = d < 0 ? -d : d;
    int gg = (a < 2 ? a : 2) + (a >= 4 ? 1 : 0);
    return d < 0 ? 3 - gg : 3 + gg;
}

// ---------------------------------------------------------------------------
// K1 (fused prep): per (bh, 4 rows):
//   - write q,k bf16 hi/lo buffers [bh][n][64]
//   - tk[bh][i][49] = q_i . w_rpe_k[:,u] ; tqT[bh][49][1024] = SCALE*k_j.w_rpe_q
// ---------------------------------------------------------------------------
__global__ void irpe_prep_k(const float* __restrict__ q, const float* __restrict__ k,
                            const float* __restrict__ w_rpe_q, const float* __restrict__ w_rpe_k,
                            u16* __restrict__ qh, u16* __restrict__ ql,
                            u16* __restrict__ kh, u16* __restrict__ kl,
                            float* __restrict__ tk, float* __restrict__ tqT) {
    const int bh = blockIdx.y, b = bh / H_, h = bh % H_;
    const int row0 = blockIdx.x * 4;
    __shared__ float qs[4][HD_], ks[4][HD_];
    const int t = threadIdx.x;
    {
        const int r = t >> 6, d = t & 63;
        const size_t gi = ((size_t)(b * N_ + row0 + r)) * C_ + h * HD_ + d;
        const float vq = q[gi], vk = k[gi];
        qs[r][d] = vq;
        ks[r][d] = vk;
        const size_t so = (((size_t)(bh << 10)) + row0 + r) * 64 + d;
        const u16 qhi = f2bf(vq), khi = f2bf(vk);
        qh[so] = qhi; ql[so] = f2bf(vq - bf2f(qhi));
        kh[so] = khi; kl[so] = f2bf(vk - bf2f(khi));
    }
    __syncthreads();
    if (t < 4 * NB_) {
        const int r = t / NB_, u = t - r * NB_;
        float dk = 0.f, dq = 0.f;
#pragma unroll
        for (int d = 0; d < HD_; ++d) {
            dk = fmaf(qs[r][d], w_rpe_k[d * NB_ + u], dk);
            dq = fmaf(ks[r][d], w_rpe_q[d * NB_ + u], dq);
        }
        tk[((size_t)bh * N_ + row0 + r) * NB_ + u] = dk;
        tqT[(((size_t)bh * NB_ + u) << 10) + row0 + r] = dq * SCALE_;
    }
}

// ---------------------------------------------------------------------------
// K0b: v -> transposed bf16 (hi only) [bh][64(d)][1024(j)]
// ---------------------------------------------------------------------------
__global__ void irpe_vt_k(const float* __restrict__ v, u16* __restrict__ vth) {
    __shared__ float tile[64][65];
    const int bh = blockIdx.y, jc0 = blockIdx.x * 64;
    const int b = bh / H_, h = bh % H_;
    const int t = threadIdx.x;
#pragma unroll
    for (int rep = 0; rep < 4; ++rep) {
        const int fl = rep * 256 + t;
        const int jr = fl >> 4, c4 = (fl & 15) * 4;
        const float4 x = *(const float4*)&v[((size_t)(b * N_ + jc0 + jr)) * C_ + h * HD_ + c4];
        tile[jr][c4] = x.x; tile[jr][c4 + 1] = x.y; tile[jr][c4 + 2] = x.z; tile[jr][c4 + 3] = x.w;
    }
    __syncthreads();
    const int d = t >> 2, jq = (t & 3) * 16;
    u32 ph[8];
#pragma unroll
    for (int jj = 0; jj < 8; ++jj) {
        const u16 h0 = f2bf(tile[jq + jj * 2][d]);
        const u16 h1 = f2bf(tile[jq + jj * 2 + 1][d]);
        ph[jj] = (u32)h0 | ((u32)h1 << 16);
    }
    const size_t dst = (((size_t)bh * 64 + d) << 10) + jc0 + jq;
    *(uint4*)&vth[dst] = make_uint4(ph[0], ph[1], ph[2], ph[3]);
    *(uint4*)&vth[dst + 8] = make_uint4(ph[4], ph[5], ph[6], ph[7]);
}

// ---------------------------------------------------------------------------
// K_main: single-sweep fused attention, bf16x3 QK / bf16 PV, wave-local P.
// Block = (bh, 64 i-rows), XCD-pinned. 4 waves; wave w owns rows w*16..+15 and
// all 4 j-tiles -> P write/read wave-local. 2 barriers/chunk. LDS ~51 KB ->
// 3 blocks/CU. attn written unnormalized (rescale kernel normalizes).
// ---------------------------------------------------------------------------
__global__ __launch_bounds__(256, 3) void irpe_attn_mfma_k(
    const u16* __restrict__ qh_g, const u16* __restrict__ ql_g,
    const u16* __restrict__ kh_g, const u16* __restrict__ kl_g,
    const u16* __restrict__ vth_g,
    const float* __restrict__ tk, const float* __restrict__ tqT,
    float* __restrict__ attn, float* __restrict__ s_arr, float* __restrict__ pre) {
    __shared__ u16 kAh[4096], kAl[4096];     // K  [64 j][64 d] swizzled  16 KB
    __shared__ u16 vAh[4096];                // vT [64 d][64 j] swizzled   8 KB
    __shared__ u16 awh[4096];                // P  [64 i][64 j] swizzled   8 KB
    __shared__ float tq_s[NB_ * 68];         // [49][68] f32            13.3 KB
    __shared__ u16 tks_s[64 * 50];           // [64][50] bf16            6.25 KB

    const int gid = blockIdx.x;
    const int xcd = gid & 7, L = gid >> 3;
    const int bh = xcd * 12 + (L >> 4);      // 12 bh per XCD, itile-inner
    const int itile = L & 15;
    const int b = bh / H_, h = bh % H_;
    const int i0 = itile * 64;
    const int t = threadIdx.x;
    const int w = t >> 6, lane = t & 63;
    const int ln4 = lane >> 4, lh15 = lane & 15;
    const int yi = itile * 2 + (w >> 1);     // wave-uniform grid-y of its rows
    const size_t tqbase = (size_t)bh * NB_ * 1024;
    const int arow0 = (bh << 10) + i0;

    // ---- persistent Q fragments (wave rows w*16+lh15) ----
    mfrag qAh[2], qAl[2];
#pragma unroll
    for (int ks = 0; ks < 2; ++ks) {
        const size_t qa = (((size_t)(bh << 10) + i0 + w * 16 + lh15) << 6) + (ln4 << 3) + (ks << 5);
        qAh[ks] = *(const mfrag*)&qh_g[qa];
        qAl[ks] = *(const mfrag*)&ql_g[qa];
    }

    // ---- chunk-invariant bucket-x: bxp[jhalf][r] = lutf(xi - xj) ----
    int bxp[2][4];
#pragma unroll
    for (int jh = 0; jh < 2; ++jh)
#pragma unroll
        for (int r = 0; r < 4; ++r) {
            const int xi = (w & 1) * 16 + ln4 * 4 + r;
            bxp[jh][r] = lutf(xi - (jh * 16 + lh15));
        }

    // ---- prefetch regs for chunk 0 ----
    mfrag kstg[4], vstg[2];
#pragma unroll
    for (int rep = 0; rep < 2; ++rep) {
        const int unit = rep * 256 + t;
        const int row = unit >> 3, un = unit & 7;
        const size_t ka = (((size_t)(bh << 10) + row) << 6) + un * 8;
        kstg[rep * 2] = *(const mfrag*)&kh_g[ka];
        kstg[rep * 2 + 1] = *(const mfrag*)&kl_g[ka];
        vstg[rep] = *(const mfrag*)&vth_g[(((size_t)(bh * 64) + row) << 10) + un * 8];
    }
    f32x4 tqpre[4];
#pragma unroll
    for (int p = 0; p < 3; ++p) {
        const int unit = p * 256 + t, u = unit >> 4, j4 = unit & 15;
        tqpre[p] = *(const f32x4*)&tqT[tqbase + ((size_t)u << 10) + (j4 << 2)];
    }
    if (t < 16) tqpre[3] = *(const f32x4*)&tqT[tqbase + ((size_t)48 << 10) + (t << 2)];

    // ---- tks -> LDS bf16 (once) ----
    {
        const size_t tkb = ((size_t)(bh << 10) + i0) * NB_;
        for (int idx = t; idx < 64 * NB_; idx += 256) {
            const int row = idx / NB_, u = idx - row * NB_;
            tks_s[row * 50 + u] = f2bf(tk[tkb + idx]);
        }
    }

    f32x4 apv[4] = {{0.f, 0.f, 0.f, 0.f}, {0.f, 0.f, 0.f, 0.f},
                    {0.f, 0.f, 0.f, 0.f}, {0.f, 0.f, 0.f, 0.f}};
    float srow[4] = {0.f, 0.f, 0.f, 0.f};

#pragma unroll 1
    for (int ch = 0; ch < 16; ++ch) {
        const int jc0 = ch << 6;

        // ---- stage K/V/tq from regs -> LDS ----
#pragma unroll
        for (int rep = 0; rep < 2; ++rep) {
            const int unit = rep * 256 + t;
            const int row = unit >> 3, un = unit & 7;
            const int ldso = row * 128 + ((un ^ (row & 7)) << 4);
            *(mfrag*)((char*)kAh + ldso) = kstg[rep * 2];
            *(mfrag*)((char*)kAl + ldso) = kstg[rep * 2 + 1];
            *(mfrag*)((char*)vAh + ldso) = vstg[rep];
        }
#pragma unroll
        for (int p = 0; p < 3; ++p) {
            const int unit = p * 256 + t, u = unit >> 4, j4 = unit & 15;
            *(f32x4*)&tq_s[u * 68 + (j4 << 2)] = tqpre[p];
        }
        if (t < 16) *(f32x4*)&tq_s[48 * 68 + (t << 2)] = tqpre[3];
        __syncthreads();   // B1: stage visible (loads were issued a chunk ago)

        // ---- QK (bf16x3): all 4 j-tiles for this wave's 16 rows ----
        f32x4 aq[4];
        __builtin_amdgcn_s_setprio(1);
#pragma unroll
        for (int ji = 0; ji < 4; ++ji) {
            const int rb = ji * 16 + lh15, swb = rb & 7;
            const mfrag bh0 = *(const mfrag*)((const char*)kAh + rb * 128 + ((ln4 ^ swb) << 4));
            const mfrag bl0 = *(const mfrag*)((const char*)kAl + rb * 128 + ((ln4 ^ swb) << 4));
            const mfrag bh1 = *(const mfrag*)((const char*)kAh + rb * 128 + (((4 + ln4) ^ swb) << 4));
            const mfrag bl1 = *(const mfrag*)((const char*)kAl + rb * 128 + (((4 + ln4) ^ swb) << 4));
            f32x4 c = {0.f, 0.f, 0.f, 0.f};
            c = __builtin_amdgcn_mfma_f32_16x16x32_bf16(qAh[0], bh0, c, 0, 0, 0);
            c = __builtin_amdgcn_mfma_f32_16x16x32_bf16(qAh[0], bl0, c, 0, 0, 0);
            c = __builtin_amdgcn_mfma_f32_16x16x32_bf16(qAl[0], bh0, c, 0, 0, 0);
            c = __builtin_amdgcn_mfma_f32_16x16x32_bf16(qAh[1], bh1, c, 0, 0, 0);
            c = __builtin_amdgcn_mfma_f32_16x16x32_bf16(qAh[1], bl1, c, 0, 0, 0);
            c = __builtin_amdgcn_mfma_f32_16x16x32_bf16(qAl[1], bh1, c, 0, 0, 0);
            aq[ji] = c;
        }
        __builtin_amdgcn_s_setprio(0);

        // ---- issue prefetch for ch+1 (drains at B2, after full compute) ----
        if (ch < 15) {
            const int jc1 = jc0 + 64;
#pragma unroll
            for (int rep = 0; rep < 2; ++rep) {
                const int unit = rep * 256 + t;
                const int row = unit >> 3, un = unit & 7;
                const size_t ka = (((size_t)(bh << 10) + jc1 + row) << 6) + un * 8;
                kstg[rep * 2] = *(const mfrag*)&kh_g[ka];
                kstg[rep * 2 + 1] = *(const mfrag*)&kl_g[ka];
                vstg[rep] = *(const mfrag*)&vth_g[(((size_t)(bh * 64) + row) << 10) + jc1 + un * 8];
            }
#pragma unroll
            for (int p = 0; p < 3; ++p) {
                const int unit = p * 256 + t, u = unit >> 4, j4 = unit & 15;
                tqpre[p] = *(const f32x4*)&tqT[tqbase + ((size_t)u << 10) + jc1 + (j4 << 2)];
            }
            if (t < 16) tqpre[3] = *(const f32x4*)&tqT[tqbase + ((size_t)48 << 10) + jc1 + (t << 2)];
        }

        // ---- bias + exp + emit (wave-local aw rows; P bf16-only) ----
#pragma unroll
        for (int ji = 0; ji < 4; ++ji) {
            const int yj = (ch << 1) + (ji >> 1);
            const int by7 = 7 * lutf(yi - yj);
            const int jl = ji * 16 + lh15;
#pragma unroll
            for (int r = 0; r < 4; ++r) {
                const int il = w * 16 + ln4 * 4 + r;
                const int bij = by7 + bxp[ji & 1][r];
                const float e = __expf(fmaf(aq[ji][r], SCALE_,
                                            bf2f(tks_s[il * 50 + bij]) + tq_s[(48 - bij) * 68 + jl]));
                srow[r] += e;
                attn[((size_t)(arow0 + il) << 10) + jc0 + jl] = e;
                const int off = il * 128 + ((jl << 1) ^ ((il & 7) << 4));
                *(u16*)((char*)awh + off) = f2bf(e);
            }
        }
        // wave-local aw: compiler inserts lgkmcnt wait before PV reads

        // ---- PV (bf16): P from own aw rows, V(hi) from vA LDS ----
        {
            const int rowA = w * 16 + lh15, sa = (rowA & 7) << 4;
            mfrag pah[2];
#pragma unroll
            for (int ks = 0; ks < 2; ++ks)
                pah[ks] = *(const mfrag*)((const char*)awh + rowA * 128 + ((((ln4 << 4) + (ks << 6))) ^ sa));
            __builtin_amdgcn_s_setprio(1);
#pragma unroll
            for (int di = 0; di < 4; ++di) {
                const int rv = di * 16 + lh15, swv = rv & 7;
                const mfrag vh0 = *(const mfrag*)((const char*)vAh + rv * 128 + ((ln4 ^ swv) << 4));
                const mfrag vh1 = *(const mfrag*)((const char*)vAh + rv * 128 + (((4 + ln4) ^ swv) << 4));
                f32x4 c = apv[di];
                c = __builtin_amdgcn_mfma_f32_16x16x32_bf16(pah[0], vh0, c, 0, 0, 0);
                c = __builtin_amdgcn_mfma_f32_16x16x32_bf16(pah[1], vh1, c, 0, 0, 0);
                apv[di] = c;
            }
            __builtin_amdgcn_s_setprio(0);
        }
        __syncthreads();   // B2: all LDS reads done; prefetch/stores drained
    }

    // ---- epilogue: row sums (butterfly over 16 lanes sharing a row) ----
    float inv[4];
#pragma unroll
    for (int r = 0; r < 4; ++r) {
        float s = srow[r];
        s += __shfl_xor(s, 1); s += __shfl_xor(s, 2);
        s += __shfl_xor(s, 4); s += __shfl_xor(s, 8);
        inv[r] = 1.0f / s;
        if (lh15 == 0) s_arr[((size_t)bh << 10) + i0 + w * 16 + ln4 * 4 + r] = s;
    }

    // ---- normalize + write pre (rpe_v added later from bs) ----
#pragma unroll
    for (int di = 0; di < 4; ++di) {
        const int d = di * 16 + lh15;
#pragma unroll
        for (int r = 0; r < 4; ++r) {
            const int i = i0 + w * 16 + ln4 * 4 + r;
            pre[((size_t)(b * N_ + i)) * C_ + h * HD_ + d] = apv[di][r] * inv[r];
        }
    }
}

// ---------------------------------------------------------------------------
// K4: rescale attn rows by 1/rowsum AND compute bucket sums bs[bh][i][49].
// ---------------------------------------------------------------------------
__global__ void irpe_rescale_bucket_k(float* __restrict__ attn, const float* __restrict__ s_arr,
                                      float* __restrict__ bs) {
    __shared__ float R[4][32][8];    // 4 KB
    __shared__ float inv_s[4];
    const int bh = blockIdx.y;
    const int i0 = blockIdx.x * 4;
    const int t = threadIdx.x;
    const int r = t >> 6, lane = t & 63;
    const int i = i0 + r, xi = i & 31;
    const float inv = 1.0f / s_arr[((size_t)bh << 10) + i];
    if (lane == 0) inv_s[r] = inv;
    for (int idx = t; idx < 4 * 32 * 8; idx += 256) ((float*)R)[idx] = 0.f;
    __syncthreads();

    const int j0 = lane * 16;
    const int yj = j0 >> 5;
    float4* rowp = (float4*)&attn[((size_t)((bh << 10) + i)) << 10];
    float4 xv0 = rowp[(j0 >> 2) + 0], xv1 = rowp[(j0 >> 2) + 1];
    float4 xv2 = rowp[(j0 >> 2) + 2], xv3 = rowp[(j0 >> 2) + 3];

    float acc = 0.f;
    int cur = lutf(xi - (j0 & 31));
#define STEP_(val, xjc) { const int bx_ = lutf(xi - (xjc));                         \
        if (bx_ != cur) { atomicAdd(&R[r][yj][cur], acc); acc = 0.f; cur = bx_; }   \
        acc += (val); }
    const int xb = j0 & 31;
    STEP_(xv0.x, xb + 0)  STEP_(xv0.y, xb + 1)  STEP_(xv0.z, xb + 2)  STEP_(xv0.w, xb + 3)
    STEP_(xv1.x, xb + 4)  STEP_(xv1.y, xb + 5)  STEP_(xv1.z, xb + 6)  STEP_(xv1.w, xb + 7)
    STEP_(xv2.x, xb + 8)  STEP_(xv2.y, xb + 9)  STEP_(xv2.z, xb + 10) STEP_(xv2.w, xb + 11)
    STEP_(xv3.x, xb + 12) STEP_(xv3.y, xb + 13) STEP_(xv3.z, xb + 14) STEP_(xv3.w, xb + 15)
    atomicAdd(&R[r][yj][cur], acc);
#undef STEP_

    xv0.x *= inv; xv0.y *= inv; xv0.z *= inv; xv0.w *= inv;
    xv1.x *= inv; xv1.y *= inv; xv1.z *= inv; xv1.w *= inv;
    xv2.x *= inv; xv2.y *= inv; xv2.z *= inv; xv2.w *= inv;
    xv3.x *= inv; xv3.y *= inv; xv3.z *= inv; xv3.w *= inv;
    rowp[(j0 >> 2) + 0] = xv0; rowp[(j0 >> 2) + 1] = xv1;
    rowp[(j0 >> 2) + 2] = xv2; rowp[(j0 >> 2) + 3] = xv3;
    __syncthreads();

    if (t < 4 * NB_) {
        const int rr = t / NB_, u = t - rr * NB_;
        const int by = u / 7, bx = u - by * 7;
        const int yi2 = (i0 + rr) >> 5;
        float s = 0.f;
#pragma unroll
        for (int yj2 = 0; yj2 < 32; ++yj2)
            if (lutf(yi2 - yj2) == by) s += R[rr][yj2][bx];
        bs[((size_t)((bh << 10) + i0 + rr)) * NB_ + u] = s * inv_s[rr];
    }
}

// ---------------------------------------------------------------------------
// K4b: pre += bs @ w_rpe_v
// ---------------------------------------------------------------------------
__global__ void irpe_addpre_k(const float* __restrict__ bs, const float* __restrict__ w_rpe_v,
                              float* __restrict__ pre) {
    __shared__ float wv[NB_ * 64];
    __shared__ float bss[16 * 52];
    const int bh = blockIdx.y, b = bh / H_, h = bh % H_;
    const int i0 = blockIdx.x * 16;
    const int t = threadIdx.x;
    for (int idx = t; idx < NB_ * 64; idx += 256) wv[idx] = w_rpe_v[idx];
    for (int idx = t; idx < 16 * NB_; idx += 256) {
        const int il = idx / NB_, u = idx - il * NB_;
        bss[il * 52 + u] = bs[((size_t)((bh << 10) + i0 + il)) * NB_ + u];
    }
    __syncthreads();
    const int il = t >> 4, d4 = (t & 15) * 4;
    f32x4 acc = {0.f, 0.f, 0.f, 0.f};
    for (int u = 0; u < NB_; ++u) {
        const float bv = bss[il * 52 + u];
        const f32x4 wvv = *(const f32x4*)&wv[u * 64 + d4];
        acc += bv * wvv;
    }
    float* p = &pre[((size_t)(b * N_ + i0 + il)) * C_ + h * HD_ + d4];
    f32x4 old = *(const f32x4*)p;
    *(f32x4*)p = old + acc;
}

// ---------------------------------------------------------------------------
// K5: projection GEMM via bf16x3 MFMA: out[m,n] = pre[m,:] . W[n,:] + b[n]
// M=8192, N=768, K=768. Block 64x64, 4 waves, K-step 64.
// ---------------------------------------------------------------------------
__global__ __launch_bounds__(256, 4) void irpe_proj_mfma_k(
    const float* __restrict__ A, const float* __restrict__ Bw,
    const float* __restrict__ bias, float* __restrict__ Cout) {
    __shared__ u16 Ah[4096], Al[4096], Bh[4096], Bl[4096];   // 32 KB
    const int bm = blockIdx.x * 64, bn = blockIdx.y * 64;
    const int t = threadIdx.x;
    const int w = t >> 6, lane = t & 63;
    const int ln4 = lane >> 4, lh15 = lane & 15;

    f32x4 acc[4] = {{0.f, 0.f, 0.f, 0.f}, {0.f, 0.f, 0.f, 0.f},
                    {0.f, 0.f, 0.f, 0.f}, {0.f, 0.f, 0.f, 0.f}};
    float bias_r[4];
#pragma unroll
    for (int ji = 0; ji < 4; ++ji) bias_r[ji] = bias[bn + ji * 16 + lh15];

    const int srow_ = t >> 3, sun = t & 7;          // staging: 32 rows/rep
    const int ldso = srow_ * 128 + ((sun ^ (srow_ & 7)) << 4);

    for (int kt = 0; kt < C_; kt += 64) {
#pragma unroll
        for (int rep = 0; rep < 2; ++rep) {
            const int row = rep * 32 + srow_;
            const int ldo = ldso + rep * 32 * 128;
            const float* ap = &A[(size_t)(bm + row) * C_ + kt + sun * 8];
            const float* bp = &Bw[(size_t)(bn + row) * C_ + kt + sun * 8];
            const float4 a0 = *(const float4*)ap, a1 = *(const float4*)(ap + 4);
            const float4 b0 = *(const float4*)bp, b1 = *(const float4*)(bp + 4);
            const float av[8] = {a0.x, a0.y, a0.z, a0.w, a1.x, a1.y, a1.z, a1.w};
            const float bv[8] = {b0.x, b0.y, b0.z, b0.w, b1.x, b1.y, b1.z, b1.w};
            u32 ahh[4], all_[4], bhh[4], bll[4];
#pragma unroll
            for (int jj = 0; jj < 4; ++jj) {
                const u16 h0 = f2bf(av[jj * 2]), h1 = f2bf(av[jj * 2 + 1]);
                ahh[jj] = (u32)h0 | ((u32)h1 << 16);
                all_[jj] = (u32)f2bf(av[jj * 2] - bf2f(h0)) | ((u32)f2bf(av[jj * 2 + 1] - bf2f(h1)) << 16);
                const u16 g0 = f2bf(bv[jj * 2]), g1 = f2bf(bv[jj * 2 + 1]);
                bhh[jj] = (u32)g0 | ((u32)g1 << 16);
                bll[jj] = (u32)f2bf(bv[jj * 2] - bf2f(g0)) | ((u32)f2bf(bv[jj * 2 + 1] - bf2f(g1)) << 16);
            }
            *(uint4*)((char*)Ah + ldo) = make_uint4(ahh[0], ahh[1], ahh[2], ahh[3]);
            *(uint4*)((char*)Al + ldo) = make_uint4(all_[0], all_[1], all_[2], all_[3]);
            *(uint4*)((char*)Bh + ldo) = make_uint4(bhh[0], bhh[1], bhh[2], bhh[3]);
            *(uint4*)((char*)Bl + ldo) = make_uint4(bll[0], bll[1], bll[2], bll[3]);
        }
        __syncthreads();

        const int ra = w * 16 + lh15, sa = ra & 7;
        const mfrag aF0h = *(const mfrag*)((const char*)Ah + ra * 128 + ((ln4 ^ sa) << 4));
        const mfrag aF0l = *(const mfrag*)((const char*)Al + ra * 128 + ((ln4 ^ sa) << 4));
        const mfrag aF1h = *(const mfrag*)((const char*)Ah + ra * 128 + (((4 + ln4) ^ sa) << 4));
        const mfrag aF1l = *(const mfrag*)((const char*)Al + ra * 128 + (((4 + ln4) ^ sa) << 4));
#pragma unroll
        for (int ji = 0; ji < 4; ++ji) {
            const int rb = ji * 16 + lh15, sb = rb & 7;
            const mfrag bF0h = *(const mfrag*)((const char*)Bh + rb * 128 + ((ln4 ^ sb) << 4));
            const mfrag bF0l = *(const mfrag*)((const char*)Bl + rb * 128 + ((ln4 ^ sb) << 4));
            const mfrag bF1h = *(const mfrag*)((const char*)Bh + rb * 128 + (((4 + ln4) ^ sb) << 4));
            const mfrag bF1l = *(const mfrag*)((const char*)Bl + rb * 128 + (((4 + ln4) ^ sb) << 4));
            f32x4 c = acc[ji];
            c = __builtin_amdgcn_mfma_f32_16x16x32_bf16(aF0h, bF0h, c, 0, 0, 0);
            c = __builtin_amdgcn_mfma_f32_16x16x32_bf16(aF0h, bF0l, c, 0, 0, 0);
            c = __builtin_amdgcn_mfma_f32_16x16x32_bf16(aF0l, bF0h, c, 0, 0, 0);
            c = __builtin_amdgcn_mfma_f32_16x16x32_bf16(aF1h, bF1h, c, 0, 0, 0);
            c = __builtin_amdgcn_mfma_f32_16x16x32_bf16(aF1h, bF1l, c, 0, 0, 0);
            c = __builtin_amdgcn_mfma_f32_16x16x32_bf16(aF1l, bF1h, c, 0, 0, 0);
            acc[ji] = c;
        }
        __syncthreads();
    }

#pragma unroll
    for (int ji = 0; ji < 4; ++ji) {
        const int col = bn + ji * 16 + lh15;
#pragma unroll
        for (int r = 0; r < 4; ++r) {
            const int row = bm + w * 16 + ln4 * 4 + r;
            Cout[(size_t)row * C_ + col] = acc[ji][r] + bias_r[ji];
        }
    }
}

// ---------------------------------------------------------------------------
extern "C" void kernel_launch(void* const* d_in, const int* in_sizes, int n_in,
                              void* d_out, int out_size, void* d_ws, size_t ws_size,
                              hipStream_t stream) {
    const float* q       = (const float*)d_in[0];
    const float* k       = (const float*)d_in[1];
    const float* v       = (const float*)d_in[2];
    const float* w_rpe_q = (const float*)d_in[3];
    const float* w_rpe_k = (const float*)d_in[4];
    const float* w_rpe_v = (const float*)d_in[5];
    const float* proj_w  = (const float*)d_in[6];
    const float* proj_b  = (const float*)d_in[7];

    float* out  = (float*)d_out;               // [B,N,C]
    float* attn = out + (size_t)B_ * N_ * C_;  // [B,H,N,N]

    char* ws = (char*)d_ws;
    float* tk    = (float*)ws; ws += (size_t)BH_ * N_ * NB_ * 4;
    float* tqT   = (float*)ws; ws += (size_t)BH_ * NB_ * N_ * 4;
    float* pre   = (float*)ws; ws += (size_t)B_ * N_ * C_ * 4;
    float* s_arr = (float*)ws; ws += (size_t)BH_ * N_ * 4;
    float* bs    = (float*)ws; ws += (size_t)BH_ * N_ * NB_ * 4;
    u16* qh  = (u16*)ws; ws += (size_t)BH_ * N_ * 64 * 2;
    u16* ql  = (u16*)ws; ws += (size_t)BH_ * N_ * 64 * 2;
    u16* kh  = (u16*)ws; ws += (size_t)BH_ * N_ * 64 * 2;
    u16* kl  = (u16*)ws; ws += (size_t)BH_ * N_ * 64 * 2;
    u16* vth = (u16*)ws; ws += (size_t)BH_ * 64 * N_ * 2;

    irpe_prep_k<<<dim3(N_ / 4, BH_), 256, 0, stream>>>(q, k, w_rpe_q, w_rpe_k,
                                                       qh, ql, kh, kl, tk, tqT);
    irpe_vt_k<<<dim3(16, BH_), 256, 0, stream>>>(v, vth);

    irpe_attn_mfma_k<<<BH_ * (N_ / 64), 256, 0, stream>>>(
        qh, ql, kh, kl, vth, tk, tqT, attn, s_arr, pre);

    irpe_rescale_bucket_k<<<dim3(N_ / 4, BH_), 256, 0, stream>>>(attn, s_arr, bs);
    irpe_addpre_k<<<dim3(N_ / 16, BH_), 256, 0, stream>>>(bs, w_rpe_v, pre);
    irpe_proj_mfma_k<<<dim3((B_ * N_) / 64, C_ / 64), 256, 0, stream>>>(pre, proj_w, proj_b, out);
}